// Round 5
// baseline (404.494 us; speedup 1.0000x reference)
//
#include <hip/hip_runtime.h>
#include <hip/hip_bf16.h>
#include <cstddef>

// ---------------------------------------------------------------------------
// GCN variational encoder: N nodes, E edges, H=128 hidden, C=64 out.
// A(HW) = (AH)W lets each layer gather in the narrow domain.
// Gathers are per-XCD L3-stream bound -> XCD column-sharding: blockIdx&1
// selects a column half; round-robin block->XCD puts each half on its own
// XCD set, halving each XCD's streamed table footprint. Two edges are
// processed per wave (sub = lane>>5) and combined with shfl_xor(32).
// ---------------------------------------------------------------------------

__global__ void k_count(const int* __restrict__ dst, int* __restrict__ deg, int e) {
    int i = blockIdx.x * 256 + threadIdx.x;
    if (i < e) atomicAdd(&deg[dst[i]], 1);
}

__global__ __launch_bounds__(256) void k_bsum(const int* __restrict__ deg,
                                              int* __restrict__ bsum, int n) {
    const int t = threadIdx.x;
    const int lane = t & 63, wv = t >> 6;
    const int i0 = blockIdx.x * 1024 + t * 4;
    int s = 0;
#pragma unroll
    for (int u = 0; u < 4; ++u) {
        int i = i0 + u;
        if (i < n) s += deg[i];
    }
#pragma unroll
    for (int d = 1; d < 64; d <<= 1) s += __shfl_down(s, d, 64);
    __shared__ int ws[4];
    if (lane == 0) ws[wv] = s;
    __syncthreads();
    if (t == 0) bsum[blockIdx.x] = ws[0] + ws[1] + ws[2] + ws[3];
}

__global__ void k_scanb(int* __restrict__ bsum, int g) {
    const int lane = threadIdx.x;
    int carry = 0;
    for (int c = 0; c < g; c += 64) {
        int i = c + lane;
        int v = (i < g) ? bsum[i] : 0;
#pragma unroll
        for (int d = 1; d < 64; d <<= 1) {
            int w = __shfl_up(v, d, 64);
            if (lane >= d) v += w;
        }
        int tot = __shfl(v, 63, 64);
        int ex = __shfl_up(v, 1, 64);
        if (lane == 0) ex = 0;
        if (i < g) bsum[i] = ex + carry;
        carry += tot;
    }
}

__global__ __launch_bounds__(256) void k_scanfinal(const int* __restrict__ deg,
                                                   const int* __restrict__ boff,
                                                   const int* __restrict__ x,
                                                   int* __restrict__ rptr,
                                                   int* __restrict__ cursor,
                                                   float* __restrict__ dinv,
                                                   int2* __restrict__ xd,
                                                   int n, int e) {
    const int t = threadIdx.x;
    const int lane = t & 63, wv = t >> 6;
    const int i0 = blockIdx.x * 1024 + t * 4;
    int d[4];
#pragma unroll
    for (int u = 0; u < 4; ++u) {
        int i = i0 + u;
        d[u] = (i < n) ? deg[i] : 0;
    }
    int v = d[0] + d[1] + d[2] + d[3];
#pragma unroll
    for (int dd = 1; dd < 64; dd <<= 1) {
        int w = __shfl_up(v, dd, 64);
        if (lane >= dd) v += w;
    }
    __shared__ int ws[4];
    if (lane == 63) ws[wv] = v;
    __syncthreads();
    int woff = 0;
    for (int w = 0; w < wv; ++w) woff += ws[w];
    int ex = __shfl_up(v, 1, 64);
    if (lane == 0) ex = 0;
    int r = boff[blockIdx.x] + woff + ex;

#pragma unroll
    for (int u = 0; u < 4; ++u) {
        int i = i0 + u;
        if (i < n) {
            rptr[i] = r;
            cursor[i] = r;
            float dv = 1.0f / sqrtf((float)(d[u] + 1));
            dinv[i] = dv;
            xd[i] = make_int2(x[i], __float_as_int(dv));
            r += d[u];
        }
    }
    if (blockIdx.x == 0 && t == 0) rptr[n] = e;
}

__global__ void k_fill(const int* __restrict__ src, const int* __restrict__ dst,
                       int* __restrict__ cursor, int* __restrict__ col, int e) {
    int i = blockIdx.x * 256 + threadIdx.x;
    if (i < e) {
        int d = dst[i];
        int pos = atomicAdd(&cursor[d], 1);
        col[pos] = src[i];
    }
}

// M = embW (V x 128) @ W1 (128 x 128); 2 rows per block
__global__ __launch_bounds__(256) void k_smallmm(const float* __restrict__ embW,
                                                 const float* __restrict__ W1,
                                                 float* __restrict__ M, int V) {
    const int r = blockIdx.x * 2 + (threadIdx.x >> 7);
    const int c = threadIdx.x & 127;
    if (r >= V) return;
    float a0 = 0.f, a1 = 0.f;
    const float* er = embW + (size_t)r * 128;
#pragma unroll 4
    for (int k = 0; k < 128; k += 2) {
        a0 = fmaf(er[k], W1[(size_t)k * 128 + c], a0);
        a1 = fmaf(er[k + 1], W1[(size_t)(k + 1) * 128 + c], a1);
    }
    M[(size_t)r * 128 + c] = a0 + a1;
}

__global__ void k_catW(const float* __restrict__ Wmu, const float* __restrict__ Wls,
                       float* __restrict__ Wcat) {
    int i = blockIdx.x * 256 + threadIdx.x;
    if (i >= 64 * 128) return;
    int k = i >> 7, c = i & 127;
    Wcat[i] = (c < 64) ? Wmu[k * 64 + c] : Wls[k * 64 + (c - 64)];
}

// layer-1 gather: M table (V<=32 rows x 128) in LDS; per edge read packed
// xd[s]={x,dinv} (8B, L2-resident) and accumulate dinv * M[x].
__global__ __launch_bounds__(256) void k_gather_l1(const float* __restrict__ M,
                                                   const int* __restrict__ rptr,
                                                   const int* __restrict__ col,
                                                   const int2* __restrict__ xd,
                                                   const float* __restrict__ b,
                                                   float* __restrict__ out,
                                                   int n, int V) {
    __shared__ float sh[32 * 128];
    for (int f = threadIdx.x; f < V * 32; f += 256)
        ((float4*)sh)[f] = ((const float4*)M)[f];
    __syncthreads();

    const int wave = threadIdx.x >> 6;
    const int lane = threadIdx.x & 63;
    const int node = blockIdx.x * 4 + wave;
    if (node >= n) return;
    const int beg = rptr[node], end = rptr[node + 1];
    int j = beg;

    float ax0 = 0.f, ay0 = 0.f, ax1 = 0.f, ay1 = 0.f;
    const int lo = 2 * lane;
    if (end - beg >= 8) {
        int s[8];
#pragma unroll
        for (int u = 0; u < 8; ++u) s[u] = col[j + u];
        j += 8;
        while (true) {
            int2 p[8];
#pragma unroll
            for (int u = 0; u < 8; ++u) p[u] = xd[s[u]];
            const bool more = (j + 8 <= end);
            int sn[8];
            if (more) {
#pragma unroll
                for (int u = 0; u < 8; ++u) sn[u] = col[j + u];
            }
#pragma unroll
            for (int u = 0; u < 8; ++u) {
                float dv = __int_as_float(p[u].y);
                float2 v = *(const float2*)&sh[p[u].x * 128 + lo];
                if (u & 1) { ax1 = fmaf(dv, v.x, ax1); ay1 = fmaf(dv, v.y, ay1); }
                else       { ax0 = fmaf(dv, v.x, ax0); ay0 = fmaf(dv, v.y, ay0); }
            }
            if (!more) break;
#pragma unroll
            for (int u = 0; u < 8; ++u) s[u] = sn[u];
            j += 8;
        }
    }
    for (; j < end; ++j) {
        int2 p = xd[col[j]];
        float dv = __int_as_float(p.y);
        float2 v = *(const float2*)&sh[p.x * 128 + lo];
        ax0 = fmaf(dv, v.x, ax0); ay0 = fmaf(dv, v.y, ay0);
    }
    int2 pn = xd[node];
    float dn = __int_as_float(pn.y);
    float2 sv = *(const float2*)&sh[pn.x * 128 + lo];
    float2 bb = ((const float2*)b)[lane];
    float ox = (ax0 + ax1 + dn * sv.x) * dn + bb.x;
    float oy = (ay0 + ay1 + dn * sv.y) * dn + bb.y;
    ((float2*)out)[(size_t)node * 64 + lane] = {ox, oy};
}

// out[r][c] = dinv[r] * sum_k act(in[r][k]) * W[k][c]
template <int K, int COUT, bool RELU>
__global__ __launch_bounds__(256) void k_matmul(const float* __restrict__ in,
                                                const float* __restrict__ W,
                                                const float* __restrict__ dinv,
                                                float* __restrict__ out, int n) {
    constexpr int BM = 64, KC = 64;
    constexpr int CT = COUT / 16;
    constexpr int LDI = KC + 4;
    __shared__ float sIn[BM * LDI];
    __shared__ float sW[KC * COUT];

    const int tid = threadIdx.x;
    const int row0 = blockIdx.x * BM;
    const int tc = tid & 15;
    const int tr = tid >> 4;

    float acc[4][CT];
#pragma unroll
    for (int j = 0; j < 4; ++j)
#pragma unroll
        for (int c = 0; c < CT; ++c) acc[j][c] = 0.f;

    for (int kc = 0; kc < K; kc += KC) {
        {
            const int r = tid >> 4;
            const int k4 = (tid & 15) * 4;
#pragma unroll
            for (int p = 0; p < BM / 16; ++p) {
                int rr = p * 16 + r;
                int gr = row0 + rr;
                float4 v = {0.f, 0.f, 0.f, 0.f};
                if (gr < n) v = *(const float4*)&in[(size_t)gr * K + kc + k4];
                if (RELU) {
                    v.x = fmaxf(v.x, 0.f); v.y = fmaxf(v.y, 0.f);
                    v.z = fmaxf(v.z, 0.f); v.w = fmaxf(v.w, 0.f);
                }
                *(float4*)&sIn[rr * LDI + k4] = v;
            }
        }
        for (int f4 = tid; f4 < KC * COUT / 4; f4 += 256) {
            *(float4*)&sW[f4 * 4] = *(const float4*)&W[(size_t)kc * COUT + f4 * 4];
        }
        __syncthreads();

#pragma unroll 8
        for (int kk = 0; kk < KC; ++kk) {
            float a[4];
#pragma unroll
            for (int j = 0; j < 4; ++j) a[j] = sIn[(tr * 4 + j) * LDI + kk];
            float4 w0 = *(const float4*)&sW[kk * COUT + tc * 4];
#pragma unroll
            for (int j = 0; j < 4; ++j) {
                acc[j][0] = fmaf(a[j], w0.x, acc[j][0]);
                acc[j][1] = fmaf(a[j], w0.y, acc[j][1]);
                acc[j][2] = fmaf(a[j], w0.z, acc[j][2]);
                acc[j][3] = fmaf(a[j], w0.w, acc[j][3]);
            }
            if constexpr (CT == 8) {
                float4 w1 = *(const float4*)&sW[kk * COUT + COUT / 2 + tc * 4];
#pragma unroll
                for (int j = 0; j < 4; ++j) {
                    acc[j][4] = fmaf(a[j], w1.x, acc[j][4]);
                    acc[j][5] = fmaf(a[j], w1.y, acc[j][5]);
                    acc[j][6] = fmaf(a[j], w1.z, acc[j][6]);
                    acc[j][7] = fmaf(a[j], w1.w, acc[j][7]);
                }
            }
        }
        __syncthreads();
    }

#pragma unroll
    for (int j = 0; j < 4; ++j) {
        int gr = row0 + tr * 4 + j;
        if (gr < n) {
            float dv = dinv[gr];
            float4 o0 = {acc[j][0] * dv, acc[j][1] * dv, acc[j][2] * dv, acc[j][3] * dv};
            *(float4*)&out[(size_t)gr * COUT + tc * 4] = o0;
            if constexpr (CT == 8) {
                float4 o1 = {acc[j][4] * dv, acc[j][5] * dv, acc[j][6] * dv, acc[j][7] * dv};
                *(float4*)&out[(size_t)gr * COUT + COUT / 2 + tc * 4] = o1;
            }
        }
    }
}

// heads matmul: out = g3 (N x 64) @ Wcat (64 x 128) + [bmu|bls] -> mu, ls
__global__ __launch_bounds__(256) void k_mm_heads(const float* __restrict__ in,
                                                  const float* __restrict__ W,
                                                  const float* __restrict__ bmu,
                                                  const float* __restrict__ bls,
                                                  float* __restrict__ mu,
                                                  float* __restrict__ ls, int n) {
    constexpr int BM = 64, KC = 64, COUT = 128;
    constexpr int LDI = KC + 4;
    __shared__ float sIn[BM * LDI];
    __shared__ float sW[KC * COUT];

    const int tid = threadIdx.x;
    const int row0 = blockIdx.x * BM;
    const int tc = tid & 15;
    const int tr = tid >> 4;

    float acc[4][8];
#pragma unroll
    for (int j = 0; j < 4; ++j)
#pragma unroll
        for (int c = 0; c < 8; ++c) acc[j][c] = 0.f;

    {
        const int r = tid >> 4;
        const int k4 = (tid & 15) * 4;
#pragma unroll
        for (int p = 0; p < BM / 16; ++p) {
            int rr = p * 16 + r;
            int gr = row0 + rr;
            float4 v = {0.f, 0.f, 0.f, 0.f};
            if (gr < n) v = *(const float4*)&in[(size_t)gr * KC + k4];
            *(float4*)&sIn[rr * LDI + k4] = v;
        }
    }
    for (int f4 = tid; f4 < KC * COUT / 4; f4 += 256) {
        *(float4*)&sW[f4 * 4] = *(const float4*)&W[f4 * 4];
    }
    __syncthreads();

#pragma unroll 8
    for (int kk = 0; kk < KC; ++kk) {
        float a[4];
#pragma unroll
        for (int j = 0; j < 4; ++j) a[j] = sIn[(tr * 4 + j) * LDI + kk];
        float4 w0 = *(const float4*)&sW[kk * COUT + tc * 4];
        float4 w1 = *(const float4*)&sW[kk * COUT + 64 + tc * 4];
#pragma unroll
        for (int j = 0; j < 4; ++j) {
            acc[j][0] = fmaf(a[j], w0.x, acc[j][0]);
            acc[j][1] = fmaf(a[j], w0.y, acc[j][1]);
            acc[j][2] = fmaf(a[j], w0.z, acc[j][2]);
            acc[j][3] = fmaf(a[j], w0.w, acc[j][3]);
            acc[j][4] = fmaf(a[j], w1.x, acc[j][4]);
            acc[j][5] = fmaf(a[j], w1.y, acc[j][5]);
            acc[j][6] = fmaf(a[j], w1.z, acc[j][6]);
            acc[j][7] = fmaf(a[j], w1.w, acc[j][7]);
        }
    }

    float4 bm = ((const float4*)bmu)[tc];
    float4 bl = ((const float4*)bls)[tc];
#pragma unroll
    for (int j = 0; j < 4; ++j) {
        int gr = row0 + tr * 4 + j;
        if (gr < n) {
            float4 o0 = {acc[j][0] + bm.x, acc[j][1] + bm.y, acc[j][2] + bm.z, acc[j][3] + bm.w};
            float4 o1 = {acc[j][4] + bl.x, acc[j][5] + bl.y, acc[j][6] + bl.z, acc[j][7] + bl.w};
            *(float4*)&mu[(size_t)gr * 64 + tc * 4] = o0;
            *(float4*)&ls[(size_t)gr * 64 + tc * 4] = o1;
        }
    }
}

// ---- XCD-sharded gathers ----
// h = blockIdx&1 picks a column half; round-robin block->XCD keeps each
// half resident on its own XCD set. Two edges per wave: sub = lane>>5
// selects the edge, shfl_xor(32) merges the two partial sums.

// 128-wide table (layer 2): half = 64 cols, float2 per lane (lane&31).
__global__ __launch_bounds__(256) void k_gather_h64(const float* __restrict__ hWs,
                                                    const int* __restrict__ rptr,
                                                    const int* __restrict__ col,
                                                    const float* __restrict__ dinv,
                                                    const float* __restrict__ b,
                                                    float* __restrict__ out, int n) {
    const int wave = threadIdx.x >> 6;
    const int lane = threadIdx.x & 63;
    const int sub = lane >> 5;
    const int h = blockIdx.x & 1;
    const int node = (blockIdx.x >> 1) * 4 + wave;
    if (node >= n) return;
    const int cf2 = h * 32 + (lane & 31);     // float2 index within 128-f row
    const float2* __restrict__ h2 = (const float2*)hWs;
    const int beg = rptr[node], end = rptr[node + 1];
    int j = beg;

    float ax0 = 0.f, ay0 = 0.f, ax1 = 0.f, ay1 = 0.f;
    if (end - beg >= 16) {
        int s[8];
#pragma unroll
        for (int u = 0; u < 8; ++u) s[u] = col[j + 2 * u + sub];
        j += 16;
        while (true) {
            float2 v[8];
#pragma unroll
            for (int u = 0; u < 8; ++u) v[u] = h2[(size_t)s[u] * 64 + cf2];
            const bool more = (j + 16 <= end);
            int sn[8];
            if (more) {
#pragma unroll
                for (int u = 0; u < 8; ++u) sn[u] = col[j + 2 * u + sub];
            }
#pragma unroll
            for (int u = 0; u < 4; ++u) { ax0 += v[u].x; ay0 += v[u].y; }
#pragma unroll
            for (int u = 4; u < 8; ++u) { ax1 += v[u].x; ay1 += v[u].y; }
            if (!more) break;
#pragma unroll
            for (int u = 0; u < 8; ++u) s[u] = sn[u];
            j += 16;
        }
    }
    for (; j + 2 <= end; j += 2) {
        float2 v = h2[(size_t)col[j + sub] * 64 + cf2];
        ax0 += v.x; ay0 += v.y;
    }
    if (j < end && sub == 0) {
        float2 v = h2[(size_t)col[j] * 64 + cf2];
        ax0 += v.x; ay0 += v.y;
    }
    float ax = ax0 + ax1, ay = ay0 + ay1;
    ax += __shfl_xor(ax, 32, 64);
    ay += __shfl_xor(ay, 32, 64);
    float2 self = h2[(size_t)node * 64 + cf2];
    float dn = dinv[node];
    float2 bb = ((const float2*)b)[cf2];
    float2 o = {(ax + self.x) * dn + bb.x, (ay + self.y) * dn + bb.y};
    if (sub == 0) ((float2*)out)[(size_t)node * 64 + cf2] = o;
}

// 64-wide table: half = 32 cols, float per lane (lane&31).
// MODE 1: out = dn*relu(o + b)  (layer 3);  MODE 2: out = o  (head pre-gather)
template <int MODE>
__global__ __launch_bounds__(256) void k_gather_h32(const float* __restrict__ hWs,
                                                    const int* __restrict__ rptr,
                                                    const int* __restrict__ col,
                                                    const float* __restrict__ dinv,
                                                    const float* __restrict__ b,
                                                    float* __restrict__ out, int n) {
    const int wave = threadIdx.x >> 6;
    const int lane = threadIdx.x & 63;
    const int sub = lane >> 5;
    const int h = blockIdx.x & 1;
    const int node = (blockIdx.x >> 1) * 4 + wave;
    if (node >= n) return;
    const int co = h * 32 + (lane & 31);
    const int beg = rptr[node], end = rptr[node + 1];
    int j = beg;

    float a0 = 0.f, a1 = 0.f;
    if (end - beg >= 16) {
        int s[8];
#pragma unroll
        for (int u = 0; u < 8; ++u) s[u] = col[j + 2 * u + sub];
        j += 16;
        while (true) {
            float v[8];
#pragma unroll
            for (int u = 0; u < 8; ++u) v[u] = hWs[(size_t)s[u] * 64 + co];
            const bool more = (j + 16 <= end);
            int sn[8];
            if (more) {
#pragma unroll
                for (int u = 0; u < 8; ++u) sn[u] = col[j + 2 * u + sub];
            }
#pragma unroll
            for (int u = 0; u < 4; ++u) a0 += v[u];
#pragma unroll
            for (int u = 4; u < 8; ++u) a1 += v[u];
            if (!more) break;
#pragma unroll
            for (int u = 0; u < 8; ++u) s[u] = sn[u];
            j += 16;
        }
    }
    for (; j + 2 <= end; j += 2) a0 += hWs[(size_t)col[j + sub] * 64 + co];
    if (j < end && sub == 0) a0 += hWs[(size_t)col[j] * 64 + co];
    float a = a0 + a1;
    a += __shfl_xor(a, 32, 64);
    float dn = dinv[node];
    float o = (a + hWs[(size_t)node * 64 + co]) * dn;
    if constexpr (MODE == 1) o = fmaxf(o + b[co], 0.f) * dn;
    if (sub == 0) out[(size_t)node * 64 + co] = o;
}

extern "C" void kernel_launch(void* const* d_in, const int* in_sizes, int n_in,
                              void* d_out, int out_size, void* d_ws, size_t ws_size,
                              hipStream_t stream) {
    const int*   x    = (const int*)d_in[0];
    const int*   ei   = (const int*)d_in[1];
    const float* embW = (const float*)d_in[2];
    const float* W1   = (const float*)d_in[3];
    const float* b1   = (const float*)d_in[4];
    const float* W2   = (const float*)d_in[5];
    const float* b2   = (const float*)d_in[6];
    const float* W3   = (const float*)d_in[7];
    const float* b3   = (const float*)d_in[8];
    const float* Wmu  = (const float*)d_in[9];
    const float* bmu  = (const float*)d_in[10];
    const float* Wls  = (const float*)d_in[11];
    const float* bls  = (const float*)d_in[12];

    const int n = in_sizes[0];
    const int e = in_sizes[1] / 2;
    const int V = in_sizes[2] / 128;
    const int* src = ei;
    const int* dst = ei + e;

    char* w = (char*)d_ws;
    auto alloc = [&](size_t bytes) {
        char* p = w;
        w += (bytes + 255) & ~(size_t)255;
        return p;
    };
    float* bufA = (float*)alloc((size_t)n * 128 * 4);
    float* bufB = (float*)alloc((size_t)n * 128 * 4);
    float* hW   = (float*)alloc((size_t)n * 128 * 4);
    int*   deg  = (int*)alloc((size_t)n * 4);
    int*   rptr = (int*)alloc((size_t)(n + 1) * 4);
    int*   cur  = (int*)alloc((size_t)n * 4);
    int*   col  = (int*)alloc((size_t)e * 4);
    float* dinv = (float*)alloc((size_t)n * 4);
    int2*  xd   = (int2*)alloc((size_t)n * 8);
    float* Wcat = (float*)alloc((size_t)64 * 128 * 4);
    float* Msm  = (float*)alloc((size_t)32 * 128 * 4);
    int*   bsum = (int*)alloc((size_t)256 * 4);

    const int nscan = (n + 1023) / 1024;

    // ---- graph prep (reused by all layers) ----
    hipMemsetAsync(deg, 0, (size_t)n * 4, stream);
    k_count<<<(e + 255) / 256, 256, 0, stream>>>(dst, deg, e);
    k_bsum <<<nscan, 256, 0, stream>>>(deg, bsum, n);
    k_scanb<<<1, 64, 0, stream>>>(bsum, nscan);
    k_scanfinal<<<nscan, 256, 0, stream>>>(deg, bsum, x, rptr, cur, dinv, xd, n, e);
    k_fill <<<(e + 255) / 256, 256, 0, stream>>>(src, dst, cur, col, e);
    k_smallmm<<<(V + 1) / 2, 256, 0, stream>>>(embW, W1, Msm, V);
    k_catW <<<(64 * 128 + 255) / 256, 256, 0, stream>>>(Wmu, Wls, Wcat);

    const int gmm = (n + 63) / 64;
    const int ggt = (n + 3) / 4;
    const int ggt2 = 2 * ggt;                 // column-sharded gathers
    float* mu = (float*)d_out;
    float* ls = (float*)d_out + (size_t)n * 64;

    // layer 1: 28-row LDS-table gather
    k_gather_l1<<<ggt, 256, 0, stream>>>(Msm, rptr, col, xd, b1, bufA, n, V);
    // layer 2: matmul (relu on load) + sharded 128-wide gather
    k_matmul<128, 128, true><<<gmm, 256, 0, stream>>>(bufA, W2, dinv, hW, n);
    k_gather_h64<<<ggt2, 256, 0, stream>>>(hW, rptr, col, dinv, b2, bufB, n);
    // layer 3: matmul 128->64 + sharded 64-wide gather, out = dinv*relu(conv3)
    k_matmul<128, 64, true><<<gmm, 256, 0, stream>>>(bufB, W3, dinv, hW, n);
    k_gather_h32<1><<<ggt2, 256, 0, stream>>>(hW, rptr, col, dinv, b3, bufA, n);
    // heads: g3 = A*(dinv*relu(conv3)) sharded gather, then 64->128 matmul
    k_gather_h32<2><<<ggt2, 256, 0, stream>>>(bufA, rptr, col, dinv, bmu, bufB, n);
    k_mm_heads<<<gmm, 256, 0, stream>>>(bufB, Wcat, bmu, bls, mu, ls, n);
}

// Round 6
// 345.176 us; speedup vs baseline: 1.1719x; 1.1719x over previous
//
#include <hip/hip_runtime.h>
#include <hip/hip_bf16.h>
#include <cstddef>

// ---------------------------------------------------------------------------
// GCN variational encoder: N nodes, E edges, H=128 hidden, C=64 out.
// A(HW) = (AH)W lets each layer gather in the narrow domain.
// Gathers are per-VMEM-instruction bound (128-wide and 64-wide rows cost the
// same) -> pack 4 edges per instruction for 64-wide tables (16 lanes x float4
// = one full row). XCD sharding reverted (R5: falsified, reuse loss ate it).
// ---------------------------------------------------------------------------

__global__ void k_count(const int* __restrict__ dst, int* __restrict__ deg, int e) {
    int i = blockIdx.x * 256 + threadIdx.x;
    if (i < e) atomicAdd(&deg[dst[i]], 1);
}

__global__ __launch_bounds__(256) void k_bsum(const int* __restrict__ deg,
                                              int* __restrict__ bsum, int n) {
    const int t = threadIdx.x;
    const int lane = t & 63, wv = t >> 6;
    const int i0 = blockIdx.x * 1024 + t * 4;
    int s = 0;
#pragma unroll
    for (int u = 0; u < 4; ++u) {
        int i = i0 + u;
        if (i < n) s += deg[i];
    }
#pragma unroll
    for (int d = 1; d < 64; d <<= 1) s += __shfl_down(s, d, 64);
    __shared__ int ws[4];
    if (lane == 0) ws[wv] = s;
    __syncthreads();
    if (t == 0) bsum[blockIdx.x] = ws[0] + ws[1] + ws[2] + ws[3];
}

__global__ void k_scanb(int* __restrict__ bsum, int g) {
    const int lane = threadIdx.x;
    int carry = 0;
    for (int c = 0; c < g; c += 64) {
        int i = c + lane;
        int v = (i < g) ? bsum[i] : 0;
#pragma unroll
        for (int d = 1; d < 64; d <<= 1) {
            int w = __shfl_up(v, d, 64);
            if (lane >= d) v += w;
        }
        int tot = __shfl(v, 63, 64);
        int ex = __shfl_up(v, 1, 64);
        if (lane == 0) ex = 0;
        if (i < g) bsum[i] = ex + carry;
        carry += tot;
    }
}

__global__ __launch_bounds__(256) void k_scanfinal(const int* __restrict__ deg,
                                                   const int* __restrict__ boff,
                                                   const int* __restrict__ x,
                                                   int* __restrict__ rptr,
                                                   int* __restrict__ cursor,
                                                   float* __restrict__ dinv,
                                                   int2* __restrict__ xd,
                                                   int n, int e) {
    const int t = threadIdx.x;
    const int lane = t & 63, wv = t >> 6;
    const int i0 = blockIdx.x * 1024 + t * 4;
    int d[4];
#pragma unroll
    for (int u = 0; u < 4; ++u) {
        int i = i0 + u;
        d[u] = (i < n) ? deg[i] : 0;
    }
    int v = d[0] + d[1] + d[2] + d[3];
#pragma unroll
    for (int dd = 1; dd < 64; dd <<= 1) {
        int w = __shfl_up(v, dd, 64);
        if (lane >= dd) v += w;
    }
    __shared__ int ws[4];
    if (lane == 63) ws[wv] = v;
    __syncthreads();
    int woff = 0;
    for (int w = 0; w < wv; ++w) woff += ws[w];
    int ex = __shfl_up(v, 1, 64);
    if (lane == 0) ex = 0;
    int r = boff[blockIdx.x] + woff + ex;

#pragma unroll
    for (int u = 0; u < 4; ++u) {
        int i = i0 + u;
        if (i < n) {
            rptr[i] = r;
            cursor[i] = r;
            float dv = 1.0f / sqrtf((float)(d[u] + 1));
            dinv[i] = dv;
            xd[i] = make_int2(x[i], __float_as_int(dv));
            r += d[u];
        }
    }
    if (blockIdx.x == 0 && t == 0) rptr[n] = e;
}

__global__ void k_fill(const int* __restrict__ src, const int* __restrict__ dst,
                       int* __restrict__ cursor, int* __restrict__ col, int e) {
    int i = blockIdx.x * 256 + threadIdx.x;
    if (i < e) {
        int d = dst[i];
        int pos = atomicAdd(&cursor[d], 1);
        col[pos] = src[i];
    }
}

// M = embW (V x 128) @ W1 (128 x 128); 2 rows per block
__global__ __launch_bounds__(256) void k_smallmm(const float* __restrict__ embW,
                                                 const float* __restrict__ W1,
                                                 float* __restrict__ M, int V) {
    const int r = blockIdx.x * 2 + (threadIdx.x >> 7);
    const int c = threadIdx.x & 127;
    if (r >= V) return;
    float a0 = 0.f, a1 = 0.f;
    const float* er = embW + (size_t)r * 128;
#pragma unroll 4
    for (int k = 0; k < 128; k += 2) {
        a0 = fmaf(er[k], W1[(size_t)k * 128 + c], a0);
        a1 = fmaf(er[k + 1], W1[(size_t)(k + 1) * 128 + c], a1);
    }
    M[(size_t)r * 128 + c] = a0 + a1;
}

__global__ void k_catW(const float* __restrict__ Wmu, const float* __restrict__ Wls,
                       float* __restrict__ Wcat) {
    int i = blockIdx.x * 256 + threadIdx.x;
    if (i >= 64 * 128) return;
    int k = i >> 7, c = i & 127;
    Wcat[i] = (c < 64) ? Wmu[k * 64 + c] : Wls[k * 64 + (c - 64)];
}

// layer-1 gather: M table (V<=32 rows x 128) in LDS; per edge read packed
// xd[s]={x,dinv} (8B, L2-resident) and accumulate dinv * M[x].
__global__ __launch_bounds__(256) void k_gather_l1(const float* __restrict__ M,
                                                   const int* __restrict__ rptr,
                                                   const int* __restrict__ col,
                                                   const int2* __restrict__ xd,
                                                   const float* __restrict__ b,
                                                   float* __restrict__ out,
                                                   int n, int V) {
    __shared__ float sh[32 * 128];
    for (int f = threadIdx.x; f < V * 32; f += 256)
        ((float4*)sh)[f] = ((const float4*)M)[f];
    __syncthreads();

    const int wave = threadIdx.x >> 6;
    const int lane = threadIdx.x & 63;
    const int node = blockIdx.x * 4 + wave;
    if (node >= n) return;
    const int beg = rptr[node], end = rptr[node + 1];
    int j = beg;

    float ax0 = 0.f, ay0 = 0.f, ax1 = 0.f, ay1 = 0.f;
    const int lo = 2 * lane;
    if (end - beg >= 8) {
        int s[8];
#pragma unroll
        for (int u = 0; u < 8; ++u) s[u] = col[j + u];
        j += 8;
        while (true) {
            int2 p[8];
#pragma unroll
            for (int u = 0; u < 8; ++u) p[u] = xd[s[u]];
            const bool more = (j + 8 <= end);
            int sn[8];
            if (more) {
#pragma unroll
                for (int u = 0; u < 8; ++u) sn[u] = col[j + u];
            }
#pragma unroll
            for (int u = 0; u < 8; ++u) {
                float dv = __int_as_float(p[u].y);
                float2 v = *(const float2*)&sh[p[u].x * 128 + lo];
                if (u & 1) { ax1 = fmaf(dv, v.x, ax1); ay1 = fmaf(dv, v.y, ay1); }
                else       { ax0 = fmaf(dv, v.x, ax0); ay0 = fmaf(dv, v.y, ay0); }
            }
            if (!more) break;
#pragma unroll
            for (int u = 0; u < 8; ++u) s[u] = sn[u];
            j += 8;
        }
    }
    for (; j < end; ++j) {
        int2 p = xd[col[j]];
        float dv = __int_as_float(p.y);
        float2 v = *(const float2*)&sh[p.x * 128 + lo];
        ax0 = fmaf(dv, v.x, ax0); ay0 = fmaf(dv, v.y, ay0);
    }
    int2 pn = xd[node];
    float dn = __int_as_float(pn.y);
    float2 sv = *(const float2*)&sh[pn.x * 128 + lo];
    float2 bb = ((const float2*)b)[lane];
    float ox = (ax0 + ax1 + dn * sv.x) * dn + bb.x;
    float oy = (ay0 + ay1 + dn * sv.y) * dn + bb.y;
    ((float2*)out)[(size_t)node * 64 + lane] = {ox, oy};
}

// out[r][c] = dinv[r] * sum_k act(in[r][k]) * W[k][c]
template <int K, int COUT, bool RELU>
__global__ __launch_bounds__(256) void k_matmul(const float* __restrict__ in,
                                                const float* __restrict__ W,
                                                const float* __restrict__ dinv,
                                                float* __restrict__ out, int n) {
    constexpr int BM = 64, KC = 64;
    constexpr int CT = COUT / 16;
    constexpr int LDI = KC + 4;
    __shared__ float sIn[BM * LDI];
    __shared__ float sW[KC * COUT];

    const int tid = threadIdx.x;
    const int row0 = blockIdx.x * BM;
    const int tc = tid & 15;
    const int tr = tid >> 4;

    float acc[4][CT];
#pragma unroll
    for (int j = 0; j < 4; ++j)
#pragma unroll
        for (int c = 0; c < CT; ++c) acc[j][c] = 0.f;

    for (int kc = 0; kc < K; kc += KC) {
        {
            const int r = tid >> 4;
            const int k4 = (tid & 15) * 4;
#pragma unroll
            for (int p = 0; p < BM / 16; ++p) {
                int rr = p * 16 + r;
                int gr = row0 + rr;
                float4 v = {0.f, 0.f, 0.f, 0.f};
                if (gr < n) v = *(const float4*)&in[(size_t)gr * K + kc + k4];
                if (RELU) {
                    v.x = fmaxf(v.x, 0.f); v.y = fmaxf(v.y, 0.f);
                    v.z = fmaxf(v.z, 0.f); v.w = fmaxf(v.w, 0.f);
                }
                *(float4*)&sIn[rr * LDI + k4] = v;
            }
        }
        for (int f4 = tid; f4 < KC * COUT / 4; f4 += 256) {
            *(float4*)&sW[f4 * 4] = *(const float4*)&W[(size_t)kc * COUT + f4 * 4];
        }
        __syncthreads();

#pragma unroll 8
        for (int kk = 0; kk < KC; ++kk) {
            float a[4];
#pragma unroll
            for (int j = 0; j < 4; ++j) a[j] = sIn[(tr * 4 + j) * LDI + kk];
            float4 w0 = *(const float4*)&sW[kk * COUT + tc * 4];
#pragma unroll
            for (int j = 0; j < 4; ++j) {
                acc[j][0] = fmaf(a[j], w0.x, acc[j][0]);
                acc[j][1] = fmaf(a[j], w0.y, acc[j][1]);
                acc[j][2] = fmaf(a[j], w0.z, acc[j][2]);
                acc[j][3] = fmaf(a[j], w0.w, acc[j][3]);
            }
            if constexpr (CT == 8) {
                float4 w1 = *(const float4*)&sW[kk * COUT + COUT / 2 + tc * 4];
#pragma unroll
                for (int j = 0; j < 4; ++j) {
                    acc[j][4] = fmaf(a[j], w1.x, acc[j][4]);
                    acc[j][5] = fmaf(a[j], w1.y, acc[j][5]);
                    acc[j][6] = fmaf(a[j], w1.z, acc[j][6]);
                    acc[j][7] = fmaf(a[j], w1.w, acc[j][7]);
                }
            }
        }
        __syncthreads();
    }

#pragma unroll
    for (int j = 0; j < 4; ++j) {
        int gr = row0 + tr * 4 + j;
        if (gr < n) {
            float dv = dinv[gr];
            float4 o0 = {acc[j][0] * dv, acc[j][1] * dv, acc[j][2] * dv, acc[j][3] * dv};
            *(float4*)&out[(size_t)gr * COUT + tc * 4] = o0;
            if constexpr (CT == 8) {
                float4 o1 = {acc[j][4] * dv, acc[j][5] * dv, acc[j][6] * dv, acc[j][7] * dv};
                *(float4*)&out[(size_t)gr * COUT + COUT / 2 + tc * 4] = o1;
            }
        }
    }
}

// heads matmul: out = g3 (N x 64) @ Wcat (64 x 128) + [bmu|bls] -> mu, ls
__global__ __launch_bounds__(256) void k_mm_heads(const float* __restrict__ in,
                                                  const float* __restrict__ W,
                                                  const float* __restrict__ bmu,
                                                  const float* __restrict__ bls,
                                                  float* __restrict__ mu,
                                                  float* __restrict__ ls, int n) {
    constexpr int BM = 64, KC = 64, COUT = 128;
    constexpr int LDI = KC + 4;
    __shared__ float sIn[BM * LDI];
    __shared__ float sW[KC * COUT];

    const int tid = threadIdx.x;
    const int row0 = blockIdx.x * BM;
    const int tc = tid & 15;
    const int tr = tid >> 4;

    float acc[4][8];
#pragma unroll
    for (int j = 0; j < 4; ++j)
#pragma unroll
        for (int c = 0; c < 8; ++c) acc[j][c] = 0.f;

    {
        const int r = tid >> 4;
        const int k4 = (tid & 15) * 4;
#pragma unroll
        for (int p = 0; p < BM / 16; ++p) {
            int rr = p * 16 + r;
            int gr = row0 + rr;
            float4 v = {0.f, 0.f, 0.f, 0.f};
            if (gr < n) v = *(const float4*)&in[(size_t)gr * KC + k4];
            *(float4*)&sIn[rr * LDI + k4] = v;
        }
    }
    for (int f4 = tid; f4 < KC * COUT / 4; f4 += 256) {
        *(float4*)&sW[f4 * 4] = *(const float4*)&W[f4 * 4];
    }
    __syncthreads();

#pragma unroll 8
    for (int kk = 0; kk < KC; ++kk) {
        float a[4];
#pragma unroll
        for (int j = 0; j < 4; ++j) a[j] = sIn[(tr * 4 + j) * LDI + kk];
        float4 w0 = *(const float4*)&sW[kk * COUT + tc * 4];
        float4 w1 = *(const float4*)&sW[kk * COUT + 64 + tc * 4];
#pragma unroll
        for (int j = 0; j < 4; ++j) {
            acc[j][0] = fmaf(a[j], w0.x, acc[j][0]);
            acc[j][1] = fmaf(a[j], w0.y, acc[j][1]);
            acc[j][2] = fmaf(a[j], w0.z, acc[j][2]);
            acc[j][3] = fmaf(a[j], w0.w, acc[j][3]);
            acc[j][4] = fmaf(a[j], w1.x, acc[j][4]);
            acc[j][5] = fmaf(a[j], w1.y, acc[j][5]);
            acc[j][6] = fmaf(a[j], w1.z, acc[j][6]);
            acc[j][7] = fmaf(a[j], w1.w, acc[j][7]);
        }
    }

    float4 bm = ((const float4*)bmu)[tc];
    float4 bl = ((const float4*)bls)[tc];
#pragma unroll
    for (int j = 0; j < 4; ++j) {
        int gr = row0 + tr * 4 + j;
        if (gr < n) {
            float4 o0 = {acc[j][0] + bm.x, acc[j][1] + bm.y, acc[j][2] + bm.z, acc[j][3] + bm.w};
            float4 o1 = {acc[j][4] + bl.x, acc[j][5] + bl.y, acc[j][6] + bl.z, acc[j][7] + bl.w};
            *(float4*)&mu[(size_t)gr * 64 + tc * 4] = o0;
            *(float4*)&ls[(size_t)gr * 64 + tc * 4] = o1;
        }
    }
}

// 128-wide gather (layer 2), unsharded (R4 form): 1 edge per wave-instruction,
// float2 per lane; unroll x8 + index prefetch.
__global__ __launch_bounds__(256) void k_gather128(const float* __restrict__ hWs,
                                                   const int* __restrict__ rptr,
                                                   const int* __restrict__ col,
                                                   const float* __restrict__ dinv,
                                                   const float* __restrict__ b,
                                                   float* __restrict__ out, int n) {
    const int wave = threadIdx.x >> 6;
    const int lane = threadIdx.x & 63;
    const int node = blockIdx.x * 4 + wave;
    if (node >= n) return;
    const int beg = rptr[node], end = rptr[node + 1];
    int j = beg;

    const float2* __restrict__ h2 = (const float2*)hWs;
    float ax0 = 0.f, ay0 = 0.f, ax1 = 0.f, ay1 = 0.f;
    if (end - beg >= 8) {
        int s[8];
#pragma unroll
        for (int u = 0; u < 8; ++u) s[u] = col[j + u];
        j += 8;
        while (true) {
            float2 v[8];
#pragma unroll
            for (int u = 0; u < 8; ++u) v[u] = h2[(size_t)s[u] * 64 + lane];
            const bool more = (j + 8 <= end);
            int sn[8];
            if (more) {
#pragma unroll
                for (int u = 0; u < 8; ++u) sn[u] = col[j + u];
            }
#pragma unroll
            for (int u = 0; u < 4; ++u) { ax0 += v[u].x; ay0 += v[u].y; }
#pragma unroll
            for (int u = 4; u < 8; ++u) { ax1 += v[u].x; ay1 += v[u].y; }
            if (!more) break;
#pragma unroll
            for (int u = 0; u < 8; ++u) s[u] = sn[u];
            j += 8;
        }
    }
    for (; j < end; ++j) {
        int s0 = col[j];
        float2 v = h2[(size_t)s0 * 64 + lane];
        ax0 += v.x; ay0 += v.y;
    }
    float2 self = h2[(size_t)node * 64 + lane];
    float dn = dinv[node];
    float2 bb = ((const float2*)b)[lane];
    float2 o = {(ax0 + ax1 + self.x) * dn + bb.x, (ay0 + ay1 + self.y) * dn + bb.y};
    ((float2*)out)[(size_t)node * 64 + lane] = o;
}

// 64-wide packed gather: 16 lanes x float4 = one full row -> 4 edges per
// wave-instruction; 16 edges per iteration (4 instrs in flight), masked (no
// serial tail). Reduce across the 4 groups with shfl_xor(16/32).
// MODE 1: out = dn*relu(o + b)  (layer 3);  MODE 2: out = o  (head pre-gather)
template <int MODE>
__global__ __launch_bounds__(256) void k_gather64p(const float* __restrict__ tab,
                                                   const int* __restrict__ rptr,
                                                   const int* __restrict__ col,
                                                   const float* __restrict__ dinv,
                                                   const float* __restrict__ b,
                                                   float* __restrict__ out, int n) {
    const int wave = threadIdx.x >> 6;
    const int lane = threadIdx.x & 63;
    const int g = lane >> 4;        // edge group 0..3
    const int q = lane & 15;        // float4 slot within row
    const int node = blockIdx.x * 4 + wave;
    if (node >= n) return;
    const int beg = rptr[node], end = rptr[node + 1];

    float4 acc = {0.f, 0.f, 0.f, 0.f};
    int j = beg;
    if (j < end) {
        // prologue: indices for first iteration
        int s[4]; bool val[4];
#pragma unroll
        for (int u = 0; u < 4; ++u) {
            int ei = j + 4 * u + g;
            val[u] = ei < end;
            s[u] = val[u] ? col[ei] : node;
        }
        j += 16;
        while (true) {
            float4 v[4];
#pragma unroll
            for (int u = 0; u < 4; ++u)
                v[u] = *(const float4*)&tab[(size_t)s[u] * 64 + q * 4];
            const bool more = j < end;
            int sn[4]; bool vn[4];
            if (more) {
#pragma unroll
                for (int u = 0; u < 4; ++u) {
                    int ei = j + 4 * u + g;
                    vn[u] = ei < end;
                    sn[u] = vn[u] ? col[ei] : node;
                }
            }
#pragma unroll
            for (int u = 0; u < 4; ++u) {
                if (val[u]) {
                    acc.x += v[u].x; acc.y += v[u].y;
                    acc.z += v[u].z; acc.w += v[u].w;
                }
            }
            if (!more) break;
#pragma unroll
            for (int u = 0; u < 4; ++u) { s[u] = sn[u]; val[u] = vn[u]; }
            j += 16;
        }
    }
    // reduce across 4 groups (lanes l, l^16, l^32, l^48)
    acc.x += __shfl_xor(acc.x, 16, 64); acc.y += __shfl_xor(acc.y, 16, 64);
    acc.z += __shfl_xor(acc.z, 16, 64); acc.w += __shfl_xor(acc.w, 16, 64);
    acc.x += __shfl_xor(acc.x, 32, 64); acc.y += __shfl_xor(acc.y, 32, 64);
    acc.z += __shfl_xor(acc.z, 32, 64); acc.w += __shfl_xor(acc.w, 32, 64);

    if (g == 0) {
        float4 self = *(const float4*)&tab[(size_t)node * 64 + q * 4];
        float dn = dinv[node];
        float4 o = {(acc.x + self.x) * dn, (acc.y + self.y) * dn,
                    (acc.z + self.z) * dn, (acc.w + self.w) * dn};
        if constexpr (MODE == 1) {
            float4 bb = ((const float4*)b)[q];
            o.x = fmaxf(o.x + bb.x, 0.f) * dn;
            o.y = fmaxf(o.y + bb.y, 0.f) * dn;
            o.z = fmaxf(o.z + bb.z, 0.f) * dn;
            o.w = fmaxf(o.w + bb.w, 0.f) * dn;
        }
        *(float4*)&out[(size_t)node * 64 + q * 4] = o;
    }
}

extern "C" void kernel_launch(void* const* d_in, const int* in_sizes, int n_in,
                              void* d_out, int out_size, void* d_ws, size_t ws_size,
                              hipStream_t stream) {
    const int*   x    = (const int*)d_in[0];
    const int*   ei   = (const int*)d_in[1];
    const float* embW = (const float*)d_in[2];
    const float* W1   = (const float*)d_in[3];
    const float* b1   = (const float*)d_in[4];
    const float* W2   = (const float*)d_in[5];
    const float* b2   = (const float*)d_in[6];
    const float* W3   = (const float*)d_in[7];
    const float* b3   = (const float*)d_in[8];
    const float* Wmu  = (const float*)d_in[9];
    const float* bmu  = (const float*)d_in[10];
    const float* Wls  = (const float*)d_in[11];
    const float* bls  = (const float*)d_in[12];

    const int n = in_sizes[0];
    const int e = in_sizes[1] / 2;
    const int V = in_sizes[2] / 128;
    const int* src = ei;
    const int* dst = ei + e;

    char* w = (char*)d_ws;
    auto alloc = [&](size_t bytes) {
        char* p = w;
        w += (bytes + 255) & ~(size_t)255;
        return p;
    };
    float* bufA = (float*)alloc((size_t)n * 128 * 4);
    float* bufB = (float*)alloc((size_t)n * 128 * 4);
    float* hW   = (float*)alloc((size_t)n * 128 * 4);
    int*   deg  = (int*)alloc((size_t)n * 4);
    int*   rptr = (int*)alloc((size_t)(n + 1) * 4);
    int*   cur  = (int*)alloc((size_t)n * 4);
    int*   col  = (int*)alloc((size_t)e * 4);
    float* dinv = (float*)alloc((size_t)n * 4);
    int2*  xd   = (int2*)alloc((size_t)n * 8);
    float* Wcat = (float*)alloc((size_t)64 * 128 * 4);
    float* Msm  = (float*)alloc((size_t)32 * 128 * 4);
    int*   bsum = (int*)alloc((size_t)256 * 4);

    const int nscan = (n + 1023) / 1024;

    // ---- graph prep (reused by all layers) ----
    hipMemsetAsync(deg, 0, (size_t)n * 4, stream);
    k_count<<<(e + 255) / 256, 256, 0, stream>>>(dst, deg, e);
    k_bsum <<<nscan, 256, 0, stream>>>(deg, bsum, n);
    k_scanb<<<1, 64, 0, stream>>>(bsum, nscan);
    k_scanfinal<<<nscan, 256, 0, stream>>>(deg, bsum, x, rptr, cur, dinv, xd, n, e);
    k_fill <<<(e + 255) / 256, 256, 0, stream>>>(src, dst, cur, col, e);
    k_smallmm<<<(V + 1) / 2, 256, 0, stream>>>(embW, W1, Msm, V);
    k_catW <<<(64 * 128 + 255) / 256, 256, 0, stream>>>(Wmu, Wls, Wcat);

    const int gmm = (n + 63) / 64;
    const int ggt = (n + 3) / 4;
    float* mu = (float*)d_out;
    float* ls = (float*)d_out + (size_t)n * 64;

    // layer 1: 28-row LDS-table gather
    k_gather_l1<<<ggt, 256, 0, stream>>>(Msm, rptr, col, xd, b1, bufA, n, V);
    // layer 2: matmul (relu on load) + 128-wide gather (unsharded)
    k_matmul<128, 128, true><<<gmm, 256, 0, stream>>>(bufA, W2, dinv, hW, n);
    k_gather128<<<ggt, 256, 0, stream>>>(hW, rptr, col, dinv, b2, bufB, n);
    // layer 3: matmul 128->64 + packed 64-wide gather, out = dinv*relu(conv3)
    k_matmul<128, 64, true><<<gmm, 256, 0, stream>>>(bufB, W3, dinv, hW, n);
    k_gather64p<1><<<ggt, 256, 0, stream>>>(hW, rptr, col, dinv, b3, bufA, n);
    // heads: g3 = A*(dinv*relu(conv3)) packed gather, then 64->128 matmul
    k_gather64p<2><<<ggt, 256, 0, stream>>>(bufA, rptr, col, dinv, bmu, bufB, n);
    k_mm_heads<<<gmm, 256, 0, stream>>>(bufB, Wcat, bmu, bls, mu, ls, n);
}

// Round 7
// 341.439 us; speedup vs baseline: 1.1847x; 1.0109x over previous
//
#include <hip/hip_runtime.h>
#include <hip/hip_bf16.h>
#include <cstddef>

// ---------------------------------------------------------------------------
// GCN variational encoder: N nodes, E edges, H=128 hidden, C=64 out.
// A(HW) = (AH)W lets each layer gather in the narrow domain.
// Gathers are per-VMEM-instruction bound -> pack multiple edges per
// instruction: 64-wide tables at 4 edges/instr (16 lanes x float4),
// 128-wide at 2 edges/instr (32 lanes x float4).
// ---------------------------------------------------------------------------

__global__ void k_count(const int* __restrict__ dst, int* __restrict__ deg, int e) {
    int i = blockIdx.x * 256 + threadIdx.x;
    if (i < e) atomicAdd(&deg[dst[i]], 1);
}

__global__ __launch_bounds__(256) void k_bsum(const int* __restrict__ deg,
                                              int* __restrict__ bsum, int n) {
    const int t = threadIdx.x;
    const int lane = t & 63, wv = t >> 6;
    const int i0 = blockIdx.x * 1024 + t * 4;
    int s = 0;
#pragma unroll
    for (int u = 0; u < 4; ++u) {
        int i = i0 + u;
        if (i < n) s += deg[i];
    }
#pragma unroll
    for (int d = 1; d < 64; d <<= 1) s += __shfl_down(s, d, 64);
    __shared__ int ws[4];
    if (lane == 0) ws[wv] = s;
    __syncthreads();
    if (t == 0) bsum[blockIdx.x] = ws[0] + ws[1] + ws[2] + ws[3];
}

__global__ void k_scanb(int* __restrict__ bsum, int g) {
    const int lane = threadIdx.x;
    int carry = 0;
    for (int c = 0; c < g; c += 64) {
        int i = c + lane;
        int v = (i < g) ? bsum[i] : 0;
#pragma unroll
        for (int d = 1; d < 64; d <<= 1) {
            int w = __shfl_up(v, d, 64);
            if (lane >= d) v += w;
        }
        int tot = __shfl(v, 63, 64);
        int ex = __shfl_up(v, 1, 64);
        if (lane == 0) ex = 0;
        if (i < g) bsum[i] = ex + carry;
        carry += tot;
    }
}

__global__ __launch_bounds__(256) void k_scanfinal(const int* __restrict__ deg,
                                                   const int* __restrict__ boff,
                                                   const int* __restrict__ x,
                                                   int* __restrict__ rptr,
                                                   int* __restrict__ cursor,
                                                   float* __restrict__ dinv,
                                                   int2* __restrict__ xd,
                                                   int n, int e) {
    const int t = threadIdx.x;
    const int lane = t & 63, wv = t >> 6;
    const int i0 = blockIdx.x * 1024 + t * 4;
    int d[4];
#pragma unroll
    for (int u = 0; u < 4; ++u) {
        int i = i0 + u;
        d[u] = (i < n) ? deg[i] : 0;
    }
    int v = d[0] + d[1] + d[2] + d[3];
#pragma unroll
    for (int dd = 1; dd < 64; dd <<= 1) {
        int w = __shfl_up(v, dd, 64);
        if (lane >= dd) v += w;
    }
    __shared__ int ws[4];
    if (lane == 63) ws[wv] = v;
    __syncthreads();
    int woff = 0;
    for (int w = 0; w < wv; ++w) woff += ws[w];
    int ex = __shfl_up(v, 1, 64);
    if (lane == 0) ex = 0;
    int r = boff[blockIdx.x] + woff + ex;

#pragma unroll
    for (int u = 0; u < 4; ++u) {
        int i = i0 + u;
        if (i < n) {
            rptr[i] = r;
            cursor[i] = r;
            float dv = 1.0f / sqrtf((float)(d[u] + 1));
            dinv[i] = dv;
            xd[i] = make_int2(x[i], __float_as_int(dv));
            r += d[u];
        }
    }
    if (blockIdx.x == 0 && t == 0) rptr[n] = e;
}

__global__ void k_fill(const int* __restrict__ src, const int* __restrict__ dst,
                       int* __restrict__ cursor, int* __restrict__ col, int e) {
    int i = blockIdx.x * 256 + threadIdx.x;
    if (i < e) {
        int d = dst[i];
        int pos = atomicAdd(&cursor[d], 1);
        col[pos] = src[i];
    }
}

// M = embW (V x 128) @ W1 (128 x 128); 2 rows per block
__global__ __launch_bounds__(256) void k_smallmm(const float* __restrict__ embW,
                                                 const float* __restrict__ W1,
                                                 float* __restrict__ M, int V) {
    const int r = blockIdx.x * 2 + (threadIdx.x >> 7);
    const int c = threadIdx.x & 127;
    if (r >= V) return;
    float a0 = 0.f, a1 = 0.f;
    const float* er = embW + (size_t)r * 128;
#pragma unroll 4
    for (int k = 0; k < 128; k += 2) {
        a0 = fmaf(er[k], W1[(size_t)k * 128 + c], a0);
        a1 = fmaf(er[k + 1], W1[(size_t)(k + 1) * 128 + c], a1);
    }
    M[(size_t)r * 128 + c] = a0 + a1;
}

__global__ void k_catW(const float* __restrict__ Wmu, const float* __restrict__ Wls,
                       float* __restrict__ Wcat) {
    int i = blockIdx.x * 256 + threadIdx.x;
    if (i >= 64 * 128) return;
    int k = i >> 7, c = i & 127;
    Wcat[i] = (c < 64) ? Wmu[k * 64 + c] : Wls[k * 64 + (c - 64)];
}

// layer-1 gather: M table (V<=32 rows x 128) in LDS; per edge read packed
// xd[s]={x,dinv} (8B, L2-resident) and accumulate dinv * M[x].
__global__ __launch_bounds__(256) void k_gather_l1(const float* __restrict__ M,
                                                   const int* __restrict__ rptr,
                                                   const int* __restrict__ col,
                                                   const int2* __restrict__ xd,
                                                   const float* __restrict__ b,
                                                   float* __restrict__ out,
                                                   int n, int V) {
    __shared__ float sh[32 * 128];
    for (int f = threadIdx.x; f < V * 32; f += 256)
        ((float4*)sh)[f] = ((const float4*)M)[f];
    __syncthreads();

    const int wave = threadIdx.x >> 6;
    const int lane = threadIdx.x & 63;
    const int node = blockIdx.x * 4 + wave;
    if (node >= n) return;
    const int beg = rptr[node], end = rptr[node + 1];
    int j = beg;

    float ax0 = 0.f, ay0 = 0.f, ax1 = 0.f, ay1 = 0.f;
    const int lo = 2 * lane;
    if (end - beg >= 8) {
        int s[8];
#pragma unroll
        for (int u = 0; u < 8; ++u) s[u] = col[j + u];
        j += 8;
        while (true) {
            int2 p[8];
#pragma unroll
            for (int u = 0; u < 8; ++u) p[u] = xd[s[u]];
            const bool more = (j + 8 <= end);
            int sn[8];
            if (more) {
#pragma unroll
                for (int u = 0; u < 8; ++u) sn[u] = col[j + u];
            }
#pragma unroll
            for (int u = 0; u < 8; ++u) {
                float dv = __int_as_float(p[u].y);
                float2 v = *(const float2*)&sh[p[u].x * 128 + lo];
                if (u & 1) { ax1 = fmaf(dv, v.x, ax1); ay1 = fmaf(dv, v.y, ay1); }
                else       { ax0 = fmaf(dv, v.x, ax0); ay0 = fmaf(dv, v.y, ay0); }
            }
            if (!more) break;
#pragma unroll
            for (int u = 0; u < 8; ++u) s[u] = sn[u];
            j += 8;
        }
    }
    for (; j < end; ++j) {
        int2 p = xd[col[j]];
        float dv = __int_as_float(p.y);
        float2 v = *(const float2*)&sh[p.x * 128 + lo];
        ax0 = fmaf(dv, v.x, ax0); ay0 = fmaf(dv, v.y, ay0);
    }
    int2 pn = xd[node];
    float dn = __int_as_float(pn.y);
    float2 sv = *(const float2*)&sh[pn.x * 128 + lo];
    float2 bb = ((const float2*)b)[lane];
    float ox = (ax0 + ax1 + dn * sv.x) * dn + bb.x;
    float oy = (ay0 + ay1 + dn * sv.y) * dn + bb.y;
    ((float2*)out)[(size_t)node * 64 + lane] = {ox, oy};
}

// out[r][c] = dinv[r] * sum_k act(in[r][k]) * W[k][c]
template <int K, int COUT, bool RELU>
__global__ __launch_bounds__(256) void k_matmul(const float* __restrict__ in,
                                                const float* __restrict__ W,
                                                const float* __restrict__ dinv,
                                                float* __restrict__ out, int n) {
    constexpr int BM = 64, KC = 64;
    constexpr int CT = COUT / 16;
    constexpr int LDI = KC + 4;
    __shared__ float sIn[BM * LDI];
    __shared__ float sW[KC * COUT];

    const int tid = threadIdx.x;
    const int row0 = blockIdx.x * BM;
    const int tc = tid & 15;
    const int tr = tid >> 4;

    float acc[4][CT];
#pragma unroll
    for (int j = 0; j < 4; ++j)
#pragma unroll
        for (int c = 0; c < CT; ++c) acc[j][c] = 0.f;

    for (int kc = 0; kc < K; kc += KC) {
        {
            const int r = tid >> 4;
            const int k4 = (tid & 15) * 4;
#pragma unroll
            for (int p = 0; p < BM / 16; ++p) {
                int rr = p * 16 + r;
                int gr = row0 + rr;
                float4 v = {0.f, 0.f, 0.f, 0.f};
                if (gr < n) v = *(const float4*)&in[(size_t)gr * K + kc + k4];
                if (RELU) {
                    v.x = fmaxf(v.x, 0.f); v.y = fmaxf(v.y, 0.f);
                    v.z = fmaxf(v.z, 0.f); v.w = fmaxf(v.w, 0.f);
                }
                *(float4*)&sIn[rr * LDI + k4] = v;
            }
        }
        for (int f4 = tid; f4 < KC * COUT / 4; f4 += 256) {
            *(float4*)&sW[f4 * 4] = *(const float4*)&W[(size_t)kc * COUT + f4 * 4];
        }
        __syncthreads();

#pragma unroll 8
        for (int kk = 0; kk < KC; ++kk) {
            float a[4];
#pragma unroll
            for (int j = 0; j < 4; ++j) a[j] = sIn[(tr * 4 + j) * LDI + kk];
            float4 w0 = *(const float4*)&sW[kk * COUT + tc * 4];
#pragma unroll
            for (int j = 0; j < 4; ++j) {
                acc[j][0] = fmaf(a[j], w0.x, acc[j][0]);
                acc[j][1] = fmaf(a[j], w0.y, acc[j][1]);
                acc[j][2] = fmaf(a[j], w0.z, acc[j][2]);
                acc[j][3] = fmaf(a[j], w0.w, acc[j][3]);
            }
            if constexpr (CT == 8) {
                float4 w1 = *(const float4*)&sW[kk * COUT + COUT / 2 + tc * 4];
#pragma unroll
                for (int j = 0; j < 4; ++j) {
                    acc[j][4] = fmaf(a[j], w1.x, acc[j][4]);
                    acc[j][5] = fmaf(a[j], w1.y, acc[j][5]);
                    acc[j][6] = fmaf(a[j], w1.z, acc[j][6]);
                    acc[j][7] = fmaf(a[j], w1.w, acc[j][7]);
                }
            }
        }
        __syncthreads();
    }

#pragma unroll
    for (int j = 0; j < 4; ++j) {
        int gr = row0 + tr * 4 + j;
        if (gr < n) {
            float dv = dinv[gr];
            float4 o0 = {acc[j][0] * dv, acc[j][1] * dv, acc[j][2] * dv, acc[j][3] * dv};
            *(float4*)&out[(size_t)gr * COUT + tc * 4] = o0;
            if constexpr (CT == 8) {
                float4 o1 = {acc[j][4] * dv, acc[j][5] * dv, acc[j][6] * dv, acc[j][7] * dv};
                *(float4*)&out[(size_t)gr * COUT + COUT / 2 + tc * 4] = o1;
            }
        }
    }
}

// heads matmul: out = g3 (N x 64) @ Wcat (64 x 128) + [bmu|bls] -> mu, ls
__global__ __launch_bounds__(256) void k_mm_heads(const float* __restrict__ in,
                                                  const float* __restrict__ W,
                                                  const float* __restrict__ bmu,
                                                  const float* __restrict__ bls,
                                                  float* __restrict__ mu,
                                                  float* __restrict__ ls, int n) {
    constexpr int BM = 64, KC = 64, COUT = 128;
    constexpr int LDI = KC + 4;
    __shared__ float sIn[BM * LDI];
    __shared__ float sW[KC * COUT];

    const int tid = threadIdx.x;
    const int row0 = blockIdx.x * BM;
    const int tc = tid & 15;
    const int tr = tid >> 4;

    float acc[4][8];
#pragma unroll
    for (int j = 0; j < 4; ++j)
#pragma unroll
        for (int c = 0; c < 8; ++c) acc[j][c] = 0.f;

    {
        const int r = tid >> 4;
        const int k4 = (tid & 15) * 4;
#pragma unroll
        for (int p = 0; p < BM / 16; ++p) {
            int rr = p * 16 + r;
            int gr = row0 + rr;
            float4 v = {0.f, 0.f, 0.f, 0.f};
            if (gr < n) v = *(const float4*)&in[(size_t)gr * KC + k4];
            *(float4*)&sIn[rr * LDI + k4] = v;
        }
    }
    for (int f4 = tid; f4 < KC * COUT / 4; f4 += 256) {
        *(float4*)&sW[f4 * 4] = *(const float4*)&W[f4 * 4];
    }
    __syncthreads();

#pragma unroll 8
    for (int kk = 0; kk < KC; ++kk) {
        float a[4];
#pragma unroll
        for (int j = 0; j < 4; ++j) a[j] = sIn[(tr * 4 + j) * LDI + kk];
        float4 w0 = *(const float4*)&sW[kk * COUT + tc * 4];
        float4 w1 = *(const float4*)&sW[kk * COUT + 64 + tc * 4];
#pragma unroll
        for (int j = 0; j < 4; ++j) {
            acc[j][0] = fmaf(a[j], w0.x, acc[j][0]);
            acc[j][1] = fmaf(a[j], w0.y, acc[j][1]);
            acc[j][2] = fmaf(a[j], w0.z, acc[j][2]);
            acc[j][3] = fmaf(a[j], w0.w, acc[j][3]);
            acc[j][4] = fmaf(a[j], w1.x, acc[j][4]);
            acc[j][5] = fmaf(a[j], w1.y, acc[j][5]);
            acc[j][6] = fmaf(a[j], w1.z, acc[j][6]);
            acc[j][7] = fmaf(a[j], w1.w, acc[j][7]);
        }
    }

    float4 bm = ((const float4*)bmu)[tc];
    float4 bl = ((const float4*)bls)[tc];
#pragma unroll
    for (int j = 0; j < 4; ++j) {
        int gr = row0 + tr * 4 + j;
        if (gr < n) {
            float4 o0 = {acc[j][0] + bm.x, acc[j][1] + bm.y, acc[j][2] + bm.z, acc[j][3] + bm.w};
            float4 o1 = {acc[j][4] + bl.x, acc[j][5] + bl.y, acc[j][6] + bl.z, acc[j][7] + bl.w};
            *(float4*)&mu[(size_t)gr * 64 + tc * 4] = o0;
            *(float4*)&ls[(size_t)gr * 64 + tc * 4] = o1;
        }
    }
}

// 128-wide packed gather (layer 2): 32 lanes x float4 = one full row ->
// 2 edges per wave-instruction; 8 loads in flight = 16 edges/iteration,
// masked (no serial tail). Reduce across the 2 groups with shfl_xor(32).
// out = (sum + self)*dn + b
__global__ __launch_bounds__(256) void k_gather128p(const float* __restrict__ tab,
                                                    const int* __restrict__ rptr,
                                                    const int* __restrict__ col,
                                                    const float* __restrict__ dinv,
                                                    const float* __restrict__ b,
                                                    float* __restrict__ out, int n) {
    const int wave = threadIdx.x >> 6;
    const int lane = threadIdx.x & 63;
    const int g = lane >> 5;        // edge group 0..1
    const int q = lane & 31;        // float4 slot within 128-f row
    const int node = blockIdx.x * 4 + wave;
    if (node >= n) return;
    const int beg = rptr[node], end = rptr[node + 1];

    float4 acc = {0.f, 0.f, 0.f, 0.f};
    int j = beg;
    if (j < end) {
        int s[8]; bool val[8];
#pragma unroll
        for (int u = 0; u < 8; ++u) {
            int ei = j + 2 * u + g;
            val[u] = ei < end;
            s[u] = val[u] ? col[ei] : node;
        }
        j += 16;
        while (true) {
            float4 v[8];
#pragma unroll
            for (int u = 0; u < 8; ++u)
                v[u] = *(const float4*)&tab[(size_t)s[u] * 128 + q * 4];
            const bool more = j < end;
            int sn[8]; bool vn[8];
            if (more) {
#pragma unroll
                for (int u = 0; u < 8; ++u) {
                    int ei = j + 2 * u + g;
                    vn[u] = ei < end;
                    sn[u] = vn[u] ? col[ei] : node;
                }
            }
#pragma unroll
            for (int u = 0; u < 8; ++u) {
                if (val[u]) {
                    acc.x += v[u].x; acc.y += v[u].y;
                    acc.z += v[u].z; acc.w += v[u].w;
                }
            }
            if (!more) break;
#pragma unroll
            for (int u = 0; u < 8; ++u) { s[u] = sn[u]; val[u] = vn[u]; }
            j += 16;
        }
    }
    acc.x += __shfl_xor(acc.x, 32, 64); acc.y += __shfl_xor(acc.y, 32, 64);
    acc.z += __shfl_xor(acc.z, 32, 64); acc.w += __shfl_xor(acc.w, 32, 64);

    if (g == 0) {
        float4 self = *(const float4*)&tab[(size_t)node * 128 + q * 4];
        float dn = dinv[node];
        float4 bb = ((const float4*)b)[q];
        float4 o = {(acc.x + self.x) * dn + bb.x, (acc.y + self.y) * dn + bb.y,
                    (acc.z + self.z) * dn + bb.z, (acc.w + self.w) * dn + bb.w};
        *(float4*)&out[(size_t)node * 128 + q * 4] = o;
    }
}

// 64-wide packed gather: 16 lanes x float4 = one full row -> 4 edges per
// wave-instruction; 16 edges per iteration, masked. shfl_xor(16/32) reduce.
// MODE 1: out = dn*relu(o + b)  (layer 3);  MODE 2: out = o  (head pre-gather)
template <int MODE>
__global__ __launch_bounds__(256) void k_gather64p(const float* __restrict__ tab,
                                                   const int* __restrict__ rptr,
                                                   const int* __restrict__ col,
                                                   const float* __restrict__ dinv,
                                                   const float* __restrict__ b,
                                                   float* __restrict__ out, int n) {
    const int wave = threadIdx.x >> 6;
    const int lane = threadIdx.x & 63;
    const int g = lane >> 4;        // edge group 0..3
    const int q = lane & 15;        // float4 slot within row
    const int node = blockIdx.x * 4 + wave;
    if (node >= n) return;
    const int beg = rptr[node], end = rptr[node + 1];

    float4 acc = {0.f, 0.f, 0.f, 0.f};
    int j = beg;
    if (j < end) {
        int s[4]; bool val[4];
#pragma unroll
        for (int u = 0; u < 4; ++u) {
            int ei = j + 4 * u + g;
            val[u] = ei < end;
            s[u] = val[u] ? col[ei] : node;
        }
        j += 16;
        while (true) {
            float4 v[4];
#pragma unroll
            for (int u = 0; u < 4; ++u)
                v[u] = *(const float4*)&tab[(size_t)s[u] * 64 + q * 4];
            const bool more = j < end;
            int sn[4]; bool vn[4];
            if (more) {
#pragma unroll
                for (int u = 0; u < 4; ++u) {
                    int ei = j + 4 * u + g;
                    vn[u] = ei < end;
                    sn[u] = vn[u] ? col[ei] : node;
                }
            }
#pragma unroll
            for (int u = 0; u < 4; ++u) {
                if (val[u]) {
                    acc.x += v[u].x; acc.y += v[u].y;
                    acc.z += v[u].z; acc.w += v[u].w;
                }
            }
            if (!more) break;
#pragma unroll
            for (int u = 0; u < 4; ++u) { s[u] = sn[u]; val[u] = vn[u]; }
            j += 16;
        }
    }
    acc.x += __shfl_xor(acc.x, 16, 64); acc.y += __shfl_xor(acc.y, 16, 64);
    acc.z += __shfl_xor(acc.z, 16, 64); acc.w += __shfl_xor(acc.w, 16, 64);
    acc.x += __shfl_xor(acc.x, 32, 64); acc.y += __shfl_xor(acc.y, 32, 64);
    acc.z += __shfl_xor(acc.z, 32, 64); acc.w += __shfl_xor(acc.w, 32, 64);

    if (g == 0) {
        float4 self = *(const float4*)&tab[(size_t)node * 64 + q * 4];
        float dn = dinv[node];
        float4 o = {(acc.x + self.x) * dn, (acc.y + self.y) * dn,
                    (acc.z + self.z) * dn, (acc.w + self.w) * dn};
        if constexpr (MODE == 1) {
            float4 bb = ((const float4*)b)[q];
            o.x = fmaxf(o.x + bb.x, 0.f) * dn;
            o.y = fmaxf(o.y + bb.y, 0.f) * dn;
            o.z = fmaxf(o.z + bb.z, 0.f) * dn;
            o.w = fmaxf(o.w + bb.w, 0.f) * dn;
        }
        *(float4*)&out[(size_t)node * 64 + q * 4] = o;
    }
}

extern "C" void kernel_launch(void* const* d_in, const int* in_sizes, int n_in,
                              void* d_out, int out_size, void* d_ws, size_t ws_size,
                              hipStream_t stream) {
    const int*   x    = (const int*)d_in[0];
    const int*   ei   = (const int*)d_in[1];
    const float* embW = (const float*)d_in[2];
    const float* W1   = (const float*)d_in[3];
    const float* b1   = (const float*)d_in[4];
    const float* W2   = (const float*)d_in[5];
    const float* b2   = (const float*)d_in[6];
    const float* W3   = (const float*)d_in[7];
    const float* b3   = (const float*)d_in[8];
    const float* Wmu  = (const float*)d_in[9];
    const float* bmu  = (const float*)d_in[10];
    const float* Wls  = (const float*)d_in[11];
    const float* bls  = (const float*)d_in[12];

    const int n = in_sizes[0];
    const int e = in_sizes[1] / 2;
    const int V = in_sizes[2] / 128;
    const int* src = ei;
    const int* dst = ei + e;

    char* w = (char*)d_ws;
    auto alloc = [&](size_t bytes) {
        char* p = w;
        w += (bytes + 255) & ~(size_t)255;
        return p;
    };
    float* bufA = (float*)alloc((size_t)n * 128 * 4);
    float* bufB = (float*)alloc((size_t)n * 128 * 4);
    float* hW   = (float*)alloc((size_t)n * 128 * 4);
    int*   deg  = (int*)alloc((size_t)n * 4);
    int*   rptr = (int*)alloc((size_t)(n + 1) * 4);
    int*   cur  = (int*)alloc((size_t)n * 4);
    int*   col  = (int*)alloc((size_t)e * 4);
    float* dinv = (float*)alloc((size_t)n * 4);
    int2*  xd   = (int2*)alloc((size_t)n * 8);
    float* Wcat = (float*)alloc((size_t)64 * 128 * 4);
    float* Msm  = (float*)alloc((size_t)32 * 128 * 4);
    int*   bsum = (int*)alloc((size_t)256 * 4);

    const int nscan = (n + 1023) / 1024;

    // ---- graph prep (reused by all layers) ----
    hipMemsetAsync(deg, 0, (size_t)n * 4, stream);
    k_count<<<(e + 255) / 256, 256, 0, stream>>>(dst, deg, e);
    k_bsum <<<nscan, 256, 0, stream>>>(deg, bsum, n);
    k_scanb<<<1, 64, 0, stream>>>(bsum, nscan);
    k_scanfinal<<<nscan, 256, 0, stream>>>(deg, bsum, x, rptr, cur, dinv, xd, n, e);
    k_fill <<<(e + 255) / 256, 256, 0, stream>>>(src, dst, cur, col, e);
    k_smallmm<<<(V + 1) / 2, 256, 0, stream>>>(embW, W1, Msm, V);
    k_catW <<<(64 * 128 + 255) / 256, 256, 0, stream>>>(Wmu, Wls, Wcat);

    const int gmm = (n + 63) / 64;
    const int ggt = (n + 3) / 4;
    float* mu = (float*)d_out;
    float* ls = (float*)d_out + (size_t)n * 64;

    // layer 1: 28-row LDS-table gather
    k_gather_l1<<<ggt, 256, 0, stream>>>(Msm, rptr, col, xd, b1, bufA, n, V);
    // layer 2: matmul (relu on load) + packed 128-wide gather (2 edges/instr)
    k_matmul<128, 128, true><<<gmm, 256, 0, stream>>>(bufA, W2, dinv, hW, n);
    k_gather128p<<<ggt, 256, 0, stream>>>(hW, rptr, col, dinv, b2, bufB, n);
    // layer 3: matmul 128->64 + packed 64-wide gather, out = dinv*relu(conv3)
    k_matmul<128, 64, true><<<gmm, 256, 0, stream>>>(bufB, W3, dinv, hW, n);
    k_gather64p<1><<<ggt, 256, 0, stream>>>(hW, rptr, col, dinv, b3, bufA, n);
    // heads: g3 = A*(dinv*relu(conv3)) packed gather, then 64->128 matmul
    k_gather64p<2><<<ggt, 256, 0, stream>>>(bufA, rptr, col, dinv, bmu, bufB, n);
    k_mm_heads<<<gmm, 256, 0, stream>>>(bufB, Wcat, bmu, bls, mu, ls, n);
}

// Round 8
// 316.227 us; speedup vs baseline: 1.2791x; 1.0797x over previous
//
#include <hip/hip_runtime.h>
#include <hip/hip_bf16.h>
#include <cstddef>

// ---------------------------------------------------------------------------
// GCN variational encoder: N nodes, E edges, H=128 hidden, C=64 out.
// A(HW) = (AH)W lets each layer gather in the narrow domain.
// Gathers: per-VMEM-instruction packed (64-wide: 4 edges/instr; 128-wide:
// 2 edges/instr); 128-wide gather sits at the compulsory per-XCD L2-fill
// floor (~186MB @ ~4TB/s).
// CSR fill: 2-pass bucketed scatter (run-reserved packed writes + LDS sort)
// to kill the 16x line-bounce write amplification of naive 4B scatter.
// ---------------------------------------------------------------------------

__global__ void k_count(const int* __restrict__ dst, int* __restrict__ deg, int e) {
    int i = blockIdx.x * 256 + threadIdx.x;
    if (i < e) atomicAdd(&deg[dst[i]], 1);
}

__global__ __launch_bounds__(256) void k_bsum(const int* __restrict__ deg,
                                              int* __restrict__ bsum, int n) {
    const int t = threadIdx.x;
    const int lane = t & 63, wv = t >> 6;
    const int i0 = blockIdx.x * 1024 + t * 4;
    int s = 0;
#pragma unroll
    for (int u = 0; u < 4; ++u) {
        int i = i0 + u;
        if (i < n) s += deg[i];
    }
#pragma unroll
    for (int d = 1; d < 64; d <<= 1) s += __shfl_down(s, d, 64);
    __shared__ int ws[4];
    if (lane == 0) ws[wv] = s;
    __syncthreads();
    if (t == 0) bsum[blockIdx.x] = ws[0] + ws[1] + ws[2] + ws[3];
}

__global__ void k_scanb(int* __restrict__ bsum, int g) {
    const int lane = threadIdx.x;
    int carry = 0;
    for (int c = 0; c < g; c += 64) {
        int i = c + lane;
        int v = (i < g) ? bsum[i] : 0;
#pragma unroll
        for (int d = 1; d < 64; d <<= 1) {
            int w = __shfl_up(v, d, 64);
            if (lane >= d) v += w;
        }
        int tot = __shfl(v, 63, 64);
        int ex = __shfl_up(v, 1, 64);
        if (lane == 0) ex = 0;
        if (i < g) bsum[i] = ex + carry;
        carry += tot;
    }
}

__global__ __launch_bounds__(256) void k_scanfinal(const int* __restrict__ deg,
                                                   const int* __restrict__ boff,
                                                   const int* __restrict__ x,
                                                   int* __restrict__ rptr,
                                                   float* __restrict__ dinv,
                                                   int2* __restrict__ xd,
                                                   int n, int e) {
    const int t = threadIdx.x;
    const int lane = t & 63, wv = t >> 6;
    const int i0 = blockIdx.x * 1024 + t * 4;
    int d[4];
#pragma unroll
    for (int u = 0; u < 4; ++u) {
        int i = i0 + u;
        d[u] = (i < n) ? deg[i] : 0;
    }
    int v = d[0] + d[1] + d[2] + d[3];
#pragma unroll
    for (int dd = 1; dd < 64; dd <<= 1) {
        int w = __shfl_up(v, dd, 64);
        if (lane >= dd) v += w;
    }
    __shared__ int ws[4];
    if (lane == 63) ws[wv] = v;
    __syncthreads();
    int woff = 0;
    for (int w = 0; w < wv; ++w) woff += ws[w];
    int ex = __shfl_up(v, 1, 64);
    if (lane == 0) ex = 0;
    int r = boff[blockIdx.x] + woff + ex;

#pragma unroll
    for (int u = 0; u < 4; ++u) {
        int i = i0 + u;
        if (i < n) {
            rptr[i] = r;
            float dv = 1.0f / sqrtf((float)(d[u] + 1));
            dinv[i] = dv;
            xd[i] = make_int2(x[i], __float_as_int(dv));
            r += d[u];
        }
    }
    if (blockIdx.x == 0 && t == 0) rptr[n] = e;
}

// ---- bucketed CSR fill ----
// Pass A: bucket = dst>>8 (256 nodes). Per 4096-edge tile: LDS histogram,
// reserve a contiguous run per bucket with ONE global atomic, then write
// packed (dlocal<<16 | src) 4B entries into the run (line-dense).
__global__ __launch_bounds__(256) void k_binA(const int* __restrict__ src,
                                              const int* __restrict__ dst,
                                              const int* __restrict__ rptr,
                                              int* __restrict__ gcur,
                                              int* __restrict__ packed,
                                              int e, int n, int nb) {
    __shared__ int hist[256];
    __shared__ int base[256];
    __shared__ int bbase[256];
    const int tid = threadIdx.x;
    const int e0 = blockIdx.x * 4096;
    const int e1 = min(e0 + 4096, e);

    hist[tid] = 0;
    bbase[tid] = rptr[min(tid << 8, n)];
    __syncthreads();
    for (int j = e0 + tid; j < e1; j += 256) atomicAdd(&hist[dst[j] >> 8], 1);
    __syncthreads();
    if (tid < nb && hist[tid] > 0) base[tid] = atomicAdd(&gcur[tid], hist[tid]);
    __syncthreads();
    hist[tid] = 0;
    __syncthreads();
    for (int j = e0 + tid; j < e1; j += 256) {
        int d = dst[j];
        int b = d >> 8;
        int r = atomicAdd(&hist[b], 1);
        packed[bbase[b] + base[b] + r] = ((d & 255) << 16) | src[j];
    }
}

// Pass B: one block per bucket. LDS-sort the bucket's packed edges into CSR
// order (per-node LDS cursors seeded from rptr), then stream to col coalesced.
#define BCAP 6144
__global__ __launch_bounds__(256) void k_binB(const int* __restrict__ packed,
                                              const int* __restrict__ rptr,
                                              int* __restrict__ col, int n) {
    __shared__ int cur[256];
    __shared__ int buf[BCAP];
    const int tid = threadIdx.x;
    const int node0 = blockIdx.x << 8;
    const int node1 = min(node0 + 256, n);
    const int ebeg = rptr[node0];
    const int eend = rptr[node1];
    const int cnt = eend - ebeg;
    cur[tid] = (node0 + tid < node1) ? (rptr[node0 + tid] - ebeg) : 0;
    __syncthreads();

    if (cnt <= BCAP) {
        for (int j = tid; j < cnt; j += 256) {
            int p = packed[ebeg + j];
            int pos = atomicAdd(&cur[p >> 16], 1);
            buf[pos] = p & 0xffff;
        }
        __syncthreads();
        for (int j = tid; j < cnt; j += 256) col[ebeg + j] = buf[j];
    } else {
        for (int j = tid; j < cnt; j += 256) {
            int p = packed[ebeg + j];
            int pos = atomicAdd(&cur[p >> 16], 1);
            col[ebeg + pos] = p & 0xffff;
        }
    }
}

// M = embW (V x 128) @ W1 (128 x 128); 2 rows per block
__global__ __launch_bounds__(256) void k_smallmm(const float* __restrict__ embW,
                                                 const float* __restrict__ W1,
                                                 float* __restrict__ M, int V) {
    const int r = blockIdx.x * 2 + (threadIdx.x >> 7);
    const int c = threadIdx.x & 127;
    if (r >= V) return;
    float a0 = 0.f, a1 = 0.f;
    const float* er = embW + (size_t)r * 128;
#pragma unroll 4
    for (int k = 0; k < 128; k += 2) {
        a0 = fmaf(er[k], W1[(size_t)k * 128 + c], a0);
        a1 = fmaf(er[k + 1], W1[(size_t)(k + 1) * 128 + c], a1);
    }
    M[(size_t)r * 128 + c] = a0 + a1;
}

__global__ void k_catW(const float* __restrict__ Wmu, const float* __restrict__ Wls,
                       float* __restrict__ Wcat) {
    int i = blockIdx.x * 256 + threadIdx.x;
    if (i >= 64 * 128) return;
    int k = i >> 7, c = i & 127;
    Wcat[i] = (c < 64) ? Wmu[k * 64 + c] : Wls[k * 64 + (c - 64)];
}

// layer-1 gather: M table (V<=32 rows x 128) in LDS; per edge read packed
// xd[s]={x,dinv} (8B, L2-resident) and accumulate dinv * M[x].
__global__ __launch_bounds__(256) void k_gather_l1(const float* __restrict__ M,
                                                   const int* __restrict__ rptr,
                                                   const int* __restrict__ col,
                                                   const int2* __restrict__ xd,
                                                   const float* __restrict__ b,
                                                   float* __restrict__ out,
                                                   int n, int V) {
    __shared__ float sh[32 * 128];
    for (int f = threadIdx.x; f < V * 32; f += 256)
        ((float4*)sh)[f] = ((const float4*)M)[f];
    __syncthreads();

    const int wave = threadIdx.x >> 6;
    const int lane = threadIdx.x & 63;
    const int node = blockIdx.x * 4 + wave;
    if (node >= n) return;
    const int beg = rptr[node], end = rptr[node + 1];
    int j = beg;

    float ax0 = 0.f, ay0 = 0.f, ax1 = 0.f, ay1 = 0.f;
    const int lo = 2 * lane;
    if (end - beg >= 8) {
        int s[8];
#pragma unroll
        for (int u = 0; u < 8; ++u) s[u] = col[j + u];
        j += 8;
        while (true) {
            int2 p[8];
#pragma unroll
            for (int u = 0; u < 8; ++u) p[u] = xd[s[u]];
            const bool more = (j + 8 <= end);
            int sn[8];
            if (more) {
#pragma unroll
                for (int u = 0; u < 8; ++u) sn[u] = col[j + u];
            }
#pragma unroll
            for (int u = 0; u < 8; ++u) {
                float dv = __int_as_float(p[u].y);
                float2 v = *(const float2*)&sh[p[u].x * 128 + lo];
                if (u & 1) { ax1 = fmaf(dv, v.x, ax1); ay1 = fmaf(dv, v.y, ay1); }
                else       { ax0 = fmaf(dv, v.x, ax0); ay0 = fmaf(dv, v.y, ay0); }
            }
            if (!more) break;
#pragma unroll
            for (int u = 0; u < 8; ++u) s[u] = sn[u];
            j += 8;
        }
    }
    for (; j < end; ++j) {
        int2 p = xd[col[j]];
        float dv = __int_as_float(p.y);
        float2 v = *(const float2*)&sh[p.x * 128 + lo];
        ax0 = fmaf(dv, v.x, ax0); ay0 = fmaf(dv, v.y, ay0);
    }
    int2 pn = xd[node];
    float dn = __int_as_float(pn.y);
    float2 sv = *(const float2*)&sh[pn.x * 128 + lo];
    float2 bb = ((const float2*)b)[lane];
    float ox = (ax0 + ax1 + dn * sv.x) * dn + bb.x;
    float oy = (ay0 + ay1 + dn * sv.y) * dn + bb.y;
    ((float2*)out)[(size_t)node * 64 + lane] = {ox, oy};
}

// out[r][c] = dinv[r] * sum_k act(in[r][k]) * W[k][c]
template <int K, int COUT, bool RELU>
__global__ __launch_bounds__(256) void k_matmul(const float* __restrict__ in,
                                                const float* __restrict__ W,
                                                const float* __restrict__ dinv,
                                                float* __restrict__ out, int n) {
    constexpr int BM = 64, KC = 64;
    constexpr int CT = COUT / 16;
    constexpr int LDI = KC + 4;
    __shared__ float sIn[BM * LDI];
    __shared__ float sW[KC * COUT];

    const int tid = threadIdx.x;
    const int row0 = blockIdx.x * BM;
    const int tc = tid & 15;
    const int tr = tid >> 4;

    float acc[4][CT];
#pragma unroll
    for (int j = 0; j < 4; ++j)
#pragma unroll
        for (int c = 0; c < CT; ++c) acc[j][c] = 0.f;

    for (int kc = 0; kc < K; kc += KC) {
        {
            const int r = tid >> 4;
            const int k4 = (tid & 15) * 4;
#pragma unroll
            for (int p = 0; p < BM / 16; ++p) {
                int rr = p * 16 + r;
                int gr = row0 + rr;
                float4 v = {0.f, 0.f, 0.f, 0.f};
                if (gr < n) v = *(const float4*)&in[(size_t)gr * K + kc + k4];
                if (RELU) {
                    v.x = fmaxf(v.x, 0.f); v.y = fmaxf(v.y, 0.f);
                    v.z = fmaxf(v.z, 0.f); v.w = fmaxf(v.w, 0.f);
                }
                *(float4*)&sIn[rr * LDI + k4] = v;
            }
        }
        for (int f4 = tid; f4 < KC * COUT / 4; f4 += 256) {
            *(float4*)&sW[f4 * 4] = *(const float4*)&W[(size_t)kc * COUT + f4 * 4];
        }
        __syncthreads();

#pragma unroll 8
        for (int kk = 0; kk < KC; ++kk) {
            float a[4];
#pragma unroll
            for (int j = 0; j < 4; ++j) a[j] = sIn[(tr * 4 + j) * LDI + kk];
            float4 w0 = *(const float4*)&sW[kk * COUT + tc * 4];
#pragma unroll
            for (int j = 0; j < 4; ++j) {
                acc[j][0] = fmaf(a[j], w0.x, acc[j][0]);
                acc[j][1] = fmaf(a[j], w0.y, acc[j][1]);
                acc[j][2] = fmaf(a[j], w0.z, acc[j][2]);
                acc[j][3] = fmaf(a[j], w0.w, acc[j][3]);
            }
            if constexpr (CT == 8) {
                float4 w1 = *(const float4*)&sW[kk * COUT + COUT / 2 + tc * 4];
#pragma unroll
                for (int j = 0; j < 4; ++j) {
                    acc[j][4] = fmaf(a[j], w1.x, acc[j][4]);
                    acc[j][5] = fmaf(a[j], w1.y, acc[j][5]);
                    acc[j][6] = fmaf(a[j], w1.z, acc[j][6]);
                    acc[j][7] = fmaf(a[j], w1.w, acc[j][7]);
                }
            }
        }
        __syncthreads();
    }

#pragma unroll
    for (int j = 0; j < 4; ++j) {
        int gr = row0 + tr * 4 + j;
        if (gr < n) {
            float dv = dinv[gr];
            float4 o0 = {acc[j][0] * dv, acc[j][1] * dv, acc[j][2] * dv, acc[j][3] * dv};
            *(float4*)&out[(size_t)gr * COUT + tc * 4] = o0;
            if constexpr (CT == 8) {
                float4 o1 = {acc[j][4] * dv, acc[j][5] * dv, acc[j][6] * dv, acc[j][7] * dv};
                *(float4*)&out[(size_t)gr * COUT + COUT / 2 + tc * 4] = o1;
            }
        }
    }
}

// heads matmul: out = g3 (N x 64) @ Wcat (64 x 128) + [bmu|bls] -> mu, ls
__global__ __launch_bounds__(256) void k_mm_heads(const float* __restrict__ in,
                                                  const float* __restrict__ W,
                                                  const float* __restrict__ bmu,
                                                  const float* __restrict__ bls,
                                                  float* __restrict__ mu,
                                                  float* __restrict__ ls, int n) {
    constexpr int BM = 64, KC = 64, COUT = 128;
    constexpr int LDI = KC + 4;
    __shared__ float sIn[BM * LDI];
    __shared__ float sW[KC * COUT];

    const int tid = threadIdx.x;
    const int row0 = blockIdx.x * BM;
    const int tc = tid & 15;
    const int tr = tid >> 4;

    float acc[4][8];
#pragma unroll
    for (int j = 0; j < 4; ++j)
#pragma unroll
        for (int c = 0; c < 8; ++c) acc[j][c] = 0.f;

    {
        const int r = tid >> 4;
        const int k4 = (tid & 15) * 4;
#pragma unroll
        for (int p = 0; p < BM / 16; ++p) {
            int rr = p * 16 + r;
            int gr = row0 + rr;
            float4 v = {0.f, 0.f, 0.f, 0.f};
            if (gr < n) v = *(const float4*)&in[(size_t)gr * KC + k4];
            *(float4*)&sIn[rr * LDI + k4] = v;
        }
    }
    for (int f4 = tid; f4 < KC * COUT / 4; f4 += 256) {
        *(float4*)&sW[f4 * 4] = *(const float4*)&W[f4 * 4];
    }
    __syncthreads();

#pragma unroll 8
    for (int kk = 0; kk < KC; ++kk) {
        float a[4];
#pragma unroll
        for (int j = 0; j < 4; ++j) a[j] = sIn[(tr * 4 + j) * LDI + kk];
        float4 w0 = *(const float4*)&sW[kk * COUT + tc * 4];
        float4 w1 = *(const float4*)&sW[kk * COUT + 64 + tc * 4];
#pragma unroll
        for (int j = 0; j < 4; ++j) {
            acc[j][0] = fmaf(a[j], w0.x, acc[j][0]);
            acc[j][1] = fmaf(a[j], w0.y, acc[j][1]);
            acc[j][2] = fmaf(a[j], w0.z, acc[j][2]);
            acc[j][3] = fmaf(a[j], w0.w, acc[j][3]);
            acc[j][4] = fmaf(a[j], w1.x, acc[j][4]);
            acc[j][5] = fmaf(a[j], w1.y, acc[j][5]);
            acc[j][6] = fmaf(a[j], w1.z, acc[j][6]);
            acc[j][7] = fmaf(a[j], w1.w, acc[j][7]);
        }
    }

    float4 bm = ((const float4*)bmu)[tc];
    float4 bl = ((const float4*)bls)[tc];
#pragma unroll
    for (int j = 0; j < 4; ++j) {
        int gr = row0 + tr * 4 + j;
        if (gr < n) {
            float4 o0 = {acc[j][0] + bm.x, acc[j][1] + bm.y, acc[j][2] + bm.z, acc[j][3] + bm.w};
            float4 o1 = {acc[j][4] + bl.x, acc[j][5] + bl.y, acc[j][6] + bl.z, acc[j][7] + bl.w};
            *(float4*)&mu[(size_t)gr * 64 + tc * 4] = o0;
            *(float4*)&ls[(size_t)gr * 64 + tc * 4] = o1;
        }
    }
}

// 128-wide packed gather (layer 2): 32 lanes x float4 = one full row ->
// 2 edges per wave-instruction; 16 edges/iteration, masked. shfl_xor(32).
__global__ __launch_bounds__(256) void k_gather128p(const float* __restrict__ tab,
                                                    const int* __restrict__ rptr,
                                                    const int* __restrict__ col,
                                                    const float* __restrict__ dinv,
                                                    const float* __restrict__ b,
                                                    float* __restrict__ out, int n) {
    const int wave = threadIdx.x >> 6;
    const int lane = threadIdx.x & 63;
    const int g = lane >> 5;
    const int q = lane & 31;
    const int node = blockIdx.x * 4 + wave;
    if (node >= n) return;
    const int beg = rptr[node], end = rptr[node + 1];

    float4 acc = {0.f, 0.f, 0.f, 0.f};
    int j = beg;
    if (j < end) {
        int s[8]; bool val[8];
#pragma unroll
        for (int u = 0; u < 8; ++u) {
            int ei = j + 2 * u + g;
            val[u] = ei < end;
            s[u] = val[u] ? col[ei] : node;
        }
        j += 16;
        while (true) {
            float4 v[8];
#pragma unroll
            for (int u = 0; u < 8; ++u)
                v[u] = *(const float4*)&tab[(size_t)s[u] * 128 + q * 4];
            const bool more = j < end;
            int sn[8]; bool vn[8];
            if (more) {
#pragma unroll
                for (int u = 0; u < 8; ++u) {
                    int ei = j + 2 * u + g;
                    vn[u] = ei < end;
                    sn[u] = vn[u] ? col[ei] : node;
                }
            }
#pragma unroll
            for (int u = 0; u < 8; ++u) {
                if (val[u]) {
                    acc.x += v[u].x; acc.y += v[u].y;
                    acc.z += v[u].z; acc.w += v[u].w;
                }
            }
            if (!more) break;
#pragma unroll
            for (int u = 0; u < 8; ++u) { s[u] = sn[u]; val[u] = vn[u]; }
            j += 16;
        }
    }
    acc.x += __shfl_xor(acc.x, 32, 64); acc.y += __shfl_xor(acc.y, 32, 64);
    acc.z += __shfl_xor(acc.z, 32, 64); acc.w += __shfl_xor(acc.w, 32, 64);

    if (g == 0) {
        float4 self = *(const float4*)&tab[(size_t)node * 128 + q * 4];
        float dn = dinv[node];
        float4 bb = ((const float4*)b)[q];
        float4 o = {(acc.x + self.x) * dn + bb.x, (acc.y + self.y) * dn + bb.y,
                    (acc.z + self.z) * dn + bb.z, (acc.w + self.w) * dn + bb.w};
        *(float4*)&out[(size_t)node * 128 + q * 4] = o;
    }
}

// 64-wide packed gather: 16 lanes x float4 = one full row -> 4 edges/instr.
// MODE 1: out = dn*relu(o + b)  (layer 3);  MODE 2: out = o  (head pre-gather)
template <int MODE>
__global__ __launch_bounds__(256) void k_gather64p(const float* __restrict__ tab,
                                                   const int* __restrict__ rptr,
                                                   const int* __restrict__ col,
                                                   const float* __restrict__ dinv,
                                                   const float* __restrict__ b,
                                                   float* __restrict__ out, int n) {
    const int wave = threadIdx.x >> 6;
    const int lane = threadIdx.x & 63;
    const int g = lane >> 4;
    const int q = lane & 15;
    const int node = blockIdx.x * 4 + wave;
    if (node >= n) return;
    const int beg = rptr[node], end = rptr[node + 1];

    float4 acc = {0.f, 0.f, 0.f, 0.f};
    int j = beg;
    if (j < end) {
        int s[4]; bool val[4];
#pragma unroll
        for (int u = 0; u < 4; ++u) {
            int ei = j + 4 * u + g;
            val[u] = ei < end;
            s[u] = val[u] ? col[ei] : node;
        }
        j += 16;
        while (true) {
            float4 v[4];
#pragma unroll
            for (int u = 0; u < 4; ++u)
                v[u] = *(const float4*)&tab[(size_t)s[u] * 64 + q * 4];
            const bool more = j < end;
            int sn[4]; bool vn[4];
            if (more) {
#pragma unroll
                for (int u = 0; u < 4; ++u) {
                    int ei = j + 4 * u + g;
                    vn[u] = ei < end;
                    sn[u] = vn[u] ? col[ei] : node;
                }
            }
#pragma unroll
            for (int u = 0; u < 4; ++u) {
                if (val[u]) {
                    acc.x += v[u].x; acc.y += v[u].y;
                    acc.z += v[u].z; acc.w += v[u].w;
                }
            }
            if (!more) break;
#pragma unroll
            for (int u = 0; u < 4; ++u) { s[u] = sn[u]; val[u] = vn[u]; }
            j += 16;
        }
    }
    acc.x += __shfl_xor(acc.x, 16, 64); acc.y += __shfl_xor(acc.y, 16, 64);
    acc.z += __shfl_xor(acc.z, 16, 64); acc.w += __shfl_xor(acc.w, 16, 64);
    acc.x += __shfl_xor(acc.x, 32, 64); acc.y += __shfl_xor(acc.y, 32, 64);
    acc.z += __shfl_xor(acc.z, 32, 64); acc.w += __shfl_xor(acc.w, 32, 64);

    if (g == 0) {
        float4 self = *(const float4*)&tab[(size_t)node * 64 + q * 4];
        float dn = dinv[node];
        float4 o = {(acc.x + self.x) * dn, (acc.y + self.y) * dn,
                    (acc.z + self.z) * dn, (acc.w + self.w) * dn};
        if constexpr (MODE == 1) {
            float4 bb = ((const float4*)b)[q];
            o.x = fmaxf(o.x + bb.x, 0.f) * dn;
            o.y = fmaxf(o.y + bb.y, 0.f) * dn;
            o.z = fmaxf(o.z + bb.z, 0.f) * dn;
            o.w = fmaxf(o.w + bb.w, 0.f) * dn;
        }
        *(float4*)&out[(size_t)node * 64 + q * 4] = o;
    }
}

extern "C" void kernel_launch(void* const* d_in, const int* in_sizes, int n_in,
                              void* d_out, int out_size, void* d_ws, size_t ws_size,
                              hipStream_t stream) {
    const int*   x    = (const int*)d_in[0];
    const int*   ei   = (const int*)d_in[1];
    const float* embW = (const float*)d_in[2];
    const float* W1   = (const float*)d_in[3];
    const float* b1   = (const float*)d_in[4];
    const float* W2   = (const float*)d_in[5];
    const float* b2   = (const float*)d_in[6];
    const float* W3   = (const float*)d_in[7];
    const float* b3   = (const float*)d_in[8];
    const float* Wmu  = (const float*)d_in[9];
    const float* bmu  = (const float*)d_in[10];
    const float* Wls  = (const float*)d_in[11];
    const float* bls  = (const float*)d_in[12];

    const int n = in_sizes[0];
    const int e = in_sizes[1] / 2;
    const int V = in_sizes[2] / 128;
    const int* src = ei;
    const int* dst = ei + e;

    char* w = (char*)d_ws;
    auto alloc = [&](size_t bytes) {
        char* p = w;
        w += (bytes + 255) & ~(size_t)255;
        return p;
    };
    float* bufA = (float*)alloc((size_t)n * 128 * 4);
    float* bufB = (float*)alloc((size_t)n * 128 * 4);
    float* hW   = (float*)alloc((size_t)n * 128 * 4);
    int*   deg  = (int*)alloc((size_t)n * 4);
    int*   rptr = (int*)alloc((size_t)(n + 1) * 4);
    int*   col  = (int*)alloc((size_t)e * 4);
    int*   pck  = (int*)alloc((size_t)e * 4);
    float* dinv = (float*)alloc((size_t)n * 4);
    int2*  xd   = (int2*)alloc((size_t)n * 8);
    float* Wcat = (float*)alloc((size_t)64 * 128 * 4);
    float* Msm  = (float*)alloc((size_t)32 * 128 * 4);
    int*   bsum = (int*)alloc((size_t)256 * 4);
    int*   gcur = (int*)alloc((size_t)256 * 4);

    const int nscan = (n + 1023) / 1024;
    const int nbuck = (n + 255) / 256;

    // ---- graph prep (reused by all layers) ----
    hipMemsetAsync(deg, 0, (size_t)n * 4, stream);
    hipMemsetAsync(gcur, 0, (size_t)256 * 4, stream);
    k_count<<<(e + 255) / 256, 256, 0, stream>>>(dst, deg, e);
    k_bsum <<<nscan, 256, 0, stream>>>(deg, bsum, n);
    k_scanb<<<1, 64, 0, stream>>>(bsum, nscan);
    k_scanfinal<<<nscan, 256, 0, stream>>>(deg, bsum, x, rptr, dinv, xd, n, e);
    k_binA <<<(e + 4095) / 4096, 256, 0, stream>>>(src, dst, rptr, gcur, pck, e, n, nbuck);
    k_binB <<<nbuck, 256, 0, stream>>>(pck, rptr, col, n);
    k_smallmm<<<(V + 1) / 2, 256, 0, stream>>>(embW, W1, Msm, V);
    k_catW <<<(64 * 128 + 255) / 256, 256, 0, stream>>>(Wmu, Wls, Wcat);

    const int gmm = (n + 63) / 64;
    const int ggt = (n + 3) / 4;
    float* mu = (float*)d_out;
    float* ls = (float*)d_out + (size_t)n * 64;

    // layer 1: 28-row LDS-table gather
    k_gather_l1<<<ggt, 256, 0, stream>>>(Msm, rptr, col, xd, b1, bufA, n, V);
    // layer 2: matmul (relu on load) + packed 128-wide gather
    k_matmul<128, 128, true><<<gmm, 256, 0, stream>>>(bufA, W2, dinv, hW, n);
    k_gather128p<<<ggt, 256, 0, stream>>>(hW, rptr, col, dinv, b2, bufB, n);
    // layer 3: matmul 128->64 + packed 64-wide gather, out = dinv*relu(conv3)
    k_matmul<128, 64, true><<<gmm, 256, 0, stream>>>(bufB, W3, dinv, hW, n);
    k_gather64p<1><<<ggt, 256, 0, stream>>>(hW, rptr, col, dinv, b3, bufA, n);
    // heads: g3 = A*(dinv*relu(conv3)) packed gather, then 64->128 matmul
    k_gather64p<2><<<ggt, 256, 0, stream>>>(bufA, rptr, col, dinv, bmu, bufB, n);
    k_mm_heads<<<gmm, 256, 0, stream>>>(bufB, Wcat, bmu, bls, mu, ls, n);
}

// Round 9
// 285.311 us; speedup vs baseline: 1.4177x; 1.1084x over previous
//
#include <hip/hip_runtime.h>
#include <hip/hip_bf16.h>
#include <cstddef>

// ---------------------------------------------------------------------------
// GCN variational encoder: N nodes, E edges, H=128 hidden, C=64 out.
// A(HW) = (AH)W lets each layer gather in the narrow domain.
// Gathers: per-VMEM-instruction packed (64-wide: 4 edges/instr; 128-wide:
// 2 edges/instr); 128-wide gather sits at the compulsory per-XCD L2-fill
// floor (~186MB @ ~3.8TB/s) -- accepted.
// CSR build: fully bucketed (bucket hist -> 256-scan -> packed scatter ->
// per-bucket node-hist+scan+sort) -- produces rptr/dinv/xd/col with no
// 50k-wide scan cascade and no 800k random global atomics.
// Matmuls: BM=128 x KC=32 tiles, 8x8 register blocking, float4 LDS reads.
// ---------------------------------------------------------------------------

// ---- bucket CSR pipeline (bucket = dst>>8; requires n <= 65536) ----

__global__ __launch_bounds__(256) void k_bcount(const int* __restrict__ dst,
                                                int* __restrict__ bcnt, int e) {
    __shared__ int h[256];
    const int tid = threadIdx.x;
    h[tid] = 0;
    __syncthreads();
    const int e0 = blockIdx.x * 4096;
    const int e1 = min(e0 + 4096, e);
    for (int j = e0 + tid; j < e1; j += 256) atomicAdd(&h[dst[j] >> 8], 1);
    __syncthreads();
    if (h[tid]) atomicAdd(&bcnt[tid], h[tid]);
}

// single block: exclusive scan bcnt[256] -> boff[257]
__global__ __launch_bounds__(256) void k_bscan(const int* __restrict__ bcnt,
                                               int* __restrict__ boff) {
    __shared__ int wsum[4];
    const int tid = threadIdx.x;
    const int lane = tid & 63, wv = tid >> 6;
    int v0 = bcnt[tid];
    int v = v0;
#pragma unroll
    for (int d = 1; d < 64; d <<= 1) {
        int w = __shfl_up(v, d, 64);
        if (lane >= d) v += w;
    }
    if (lane == 63) wsum[wv] = v;
    __syncthreads();
    int woff = 0;
    for (int w = 0; w < wv; ++w) woff += wsum[w];
    int excl = woff + v - v0;
    boff[tid] = excl;
    if (tid == 255) boff[256] = excl + v0;
}

// scatter edges as packed (dlocal<<16 | src) into per-bucket runs
__global__ __launch_bounds__(256) void k_binA2(const int* __restrict__ src,
                                               const int* __restrict__ dst,
                                               const int* __restrict__ boff,
                                               int* __restrict__ gcur,
                                               int* __restrict__ packed,
                                               int e, int nb) {
    __shared__ int hist[256];
    __shared__ int base[256];
    __shared__ int bbase[256];
    const int tid = threadIdx.x;
    const int e0 = blockIdx.x * 4096;
    const int e1 = min(e0 + 4096, e);

    hist[tid] = 0;
    bbase[tid] = boff[tid];
    __syncthreads();
    for (int j = e0 + tid; j < e1; j += 256) atomicAdd(&hist[dst[j] >> 8], 1);
    __syncthreads();
    if (tid < nb && hist[tid] > 0) base[tid] = atomicAdd(&gcur[tid], hist[tid]);
    __syncthreads();
    hist[tid] = 0;
    __syncthreads();
    for (int j = e0 + tid; j < e1; j += 256) {
        int d = dst[j];
        int b = d >> 8;
        int r = atomicAdd(&hist[b], 1);
        packed[bbase[b] + base[b] + r] = ((d & 255) << 16) | src[j];
    }
}

// per bucket: node hist + in-block scan -> rptr/dinv/xd; LDS sort -> col
#define BCAP 6144
__global__ __launch_bounds__(256) void k_binB2(const int* __restrict__ packed,
                                               const int* __restrict__ boff,
                                               const int* __restrict__ x,
                                               int* __restrict__ rptr,
                                               float* __restrict__ dinv,
                                               int2* __restrict__ xd,
                                               int* __restrict__ col,
                                               int n) {
    __shared__ int hist[256];
    __shared__ int cur[256];
    __shared__ int wsum[4];
    __shared__ int buf[BCAP];
    const int tid = threadIdx.x;
    const int lane = tid & 63, wv = tid >> 6;
    const int node0 = blockIdx.x << 8;
    const int node1 = min(node0 + 256, n);
    const int ebeg = boff[blockIdx.x];
    const int eend = boff[blockIdx.x + 1];
    const int cnt = eend - ebeg;

    hist[tid] = 0;
    __syncthreads();
    for (int j = tid; j < cnt; j += 256) atomicAdd(&hist[packed[ebeg + j] >> 16], 1);
    __syncthreads();
    const int deg = hist[tid];
    int v = deg;
#pragma unroll
    for (int d = 1; d < 64; d <<= 1) {
        int w = __shfl_up(v, d, 64);
        if (lane >= d) v += w;
    }
    if (lane == 63) wsum[wv] = v;
    __syncthreads();
    int woff = 0;
    for (int w = 0; w < wv; ++w) woff += wsum[w];
    const int excl = woff + v - deg;
    cur[tid] = excl;
    const int node = node0 + tid;
    if (node < node1) {
        rptr[node] = ebeg + excl;
        float dv = 1.0f / sqrtf((float)(deg + 1));
        dinv[node] = dv;
        xd[node] = make_int2(x[node], __float_as_int(dv));
    }
    if (node1 == n && tid == 0) rptr[n] = eend;
    __syncthreads();

    if (cnt <= BCAP) {
        for (int j = tid; j < cnt; j += 256) {
            int p = packed[ebeg + j];
            int pos = atomicAdd(&cur[p >> 16], 1);
            buf[pos] = p & 0xffff;
        }
        __syncthreads();
        for (int j = tid; j < cnt; j += 256) col[ebeg + j] = buf[j];
    } else {
        for (int j = tid; j < cnt; j += 256) {
            int p = packed[ebeg + j];
            int pos = atomicAdd(&cur[p >> 16], 1);
            col[ebeg + pos] = p & 0xffff;
        }
    }
}

// M = embW (V x 128) @ W1 (128 x 128); 2 rows per block
__global__ __launch_bounds__(256) void k_smallmm(const float* __restrict__ embW,
                                                 const float* __restrict__ W1,
                                                 float* __restrict__ M, int V) {
    const int r = blockIdx.x * 2 + (threadIdx.x >> 7);
    const int c = threadIdx.x & 127;
    if (r >= V) return;
    float a0 = 0.f, a1 = 0.f;
    const float* er = embW + (size_t)r * 128;
#pragma unroll 4
    for (int k = 0; k < 128; k += 2) {
        a0 = fmaf(er[k], W1[(size_t)k * 128 + c], a0);
        a1 = fmaf(er[k + 1], W1[(size_t)(k + 1) * 128 + c], a1);
    }
    M[(size_t)r * 128 + c] = a0 + a1;
}

__global__ void k_catW(const float* __restrict__ Wmu, const float* __restrict__ Wls,
                       float* __restrict__ Wcat) {
    int i = blockIdx.x * 256 + threadIdx.x;
    if (i >= 64 * 128) return;
    int k = i >> 7, c = i & 127;
    Wcat[i] = (c < 64) ? Wmu[k * 64 + c] : Wls[k * 64 + (c - 64)];
}

// layer-1 gather: M table (V<=32 rows x 128) in LDS; per edge read packed
// xd[s]={x,dinv} (8B, L2-resident) and accumulate dinv * M[x].
__global__ __launch_bounds__(256) void k_gather_l1(const float* __restrict__ M,
                                                   const int* __restrict__ rptr,
                                                   const int* __restrict__ col,
                                                   const int2* __restrict__ xd,
                                                   const float* __restrict__ b,
                                                   float* __restrict__ out,
                                                   int n, int V) {
    __shared__ float sh[32 * 128];
    for (int f = threadIdx.x; f < V * 32; f += 256)
        ((float4*)sh)[f] = ((const float4*)M)[f];
    __syncthreads();

    const int wave = threadIdx.x >> 6;
    const int lane = threadIdx.x & 63;
    const int node = blockIdx.x * 4 + wave;
    if (node >= n) return;
    const int beg = rptr[node], end = rptr[node + 1];
    int j = beg;

    float ax0 = 0.f, ay0 = 0.f, ax1 = 0.f, ay1 = 0.f;
    const int lo = 2 * lane;
    if (end - beg >= 8) {
        int s[8];
#pragma unroll
        for (int u = 0; u < 8; ++u) s[u] = col[j + u];
        j += 8;
        while (true) {
            int2 p[8];
#pragma unroll
            for (int u = 0; u < 8; ++u) p[u] = xd[s[u]];
            const bool more = (j + 8 <= end);
            int sn[8];
            if (more) {
#pragma unroll
                for (int u = 0; u < 8; ++u) sn[u] = col[j + u];
            }
#pragma unroll
            for (int u = 0; u < 8; ++u) {
                float dv = __int_as_float(p[u].y);
                float2 v = *(const float2*)&sh[p[u].x * 128 + lo];
                if (u & 1) { ax1 = fmaf(dv, v.x, ax1); ay1 = fmaf(dv, v.y, ay1); }
                else       { ax0 = fmaf(dv, v.x, ax0); ay0 = fmaf(dv, v.y, ay0); }
            }
            if (!more) break;
#pragma unroll
            for (int u = 0; u < 8; ++u) s[u] = sn[u];
            j += 8;
        }
    }
    for (; j < end; ++j) {
        int2 p = xd[col[j]];
        float dv = __int_as_float(p.y);
        float2 v = *(const float2*)&sh[p.x * 128 + lo];
        ax0 = fmaf(dv, v.x, ax0); ay0 = fmaf(dv, v.y, ay0);
    }
    int2 pn = xd[node];
    float dn = __int_as_float(pn.y);
    float2 sv = *(const float2*)&sh[pn.x * 128 + lo];
    float2 bb = ((const float2*)b)[lane];
    float ox = (ax0 + ax1 + dn * sv.x) * dn + bb.x;
    float oy = (ay0 + ay1 + dn * sv.y) * dn + bb.y;
    ((float2*)out)[(size_t)node * 64 + lane] = {ox, oy};
}

// out[r][c] = dinv[r] * sum_k act(in[r][k]) * W[k][c]
// BM=128, KC=32; 256 threads; per-thread 8 rows x CT*4 cols register tile.
template <int K, int COUT, bool RELU>
__global__ __launch_bounds__(256) void k_matmul(const float* __restrict__ in,
                                                const float* __restrict__ W,
                                                const float* __restrict__ dinv,
                                                float* __restrict__ out, int n) {
    constexpr int BM = 128, KC = 32, LDI = KC + 4;
    constexpr int CT = COUT / 16;      // 8 (COUT=128) or 4 (COUT=64)
    __shared__ float sIn[BM * LDI];
    __shared__ float sW[KC * COUT];

    const int tid = threadIdx.x;
    const int row0 = blockIdx.x * BM;
    const int tc = tid & 15;           // 16 col groups
    const int tr = tid >> 4;           // 16 row groups of 8 rows

    float acc[8][CT];
#pragma unroll
    for (int j = 0; j < 8; ++j)
#pragma unroll
        for (int c = 0; c < CT; ++c) acc[j][c] = 0.f;

    const int sr = tid >> 3;           // 0..31 (staging row group)
    const int sk = (tid & 7) * 4;      // 0..28 (staging k4)

    for (int kc = 0; kc < K; kc += KC) {
        // stage input tile (128 x 32), act on load
#pragma unroll
        for (int p = 0; p < 4; ++p) {
            int rr = p * 32 + sr;
            int gr = row0 + rr;
            float4 v = {0.f, 0.f, 0.f, 0.f};
            if (gr < n) v = *(const float4*)&in[(size_t)gr * K + kc + sk];
            if (RELU) {
                v.x = fmaxf(v.x, 0.f); v.y = fmaxf(v.y, 0.f);
                v.z = fmaxf(v.z, 0.f); v.w = fmaxf(v.w, 0.f);
            }
            *(float4*)&sIn[rr * LDI + sk] = v;
        }
        // stage W slab (KC x COUT)
        for (int f4 = tid; f4 < KC * COUT / 4; f4 += 256)
            *(float4*)&sW[f4 * 4] = *(const float4*)&W[(size_t)kc * COUT + f4 * 4];
        __syncthreads();

        for (int kk = 0; kk < KC; kk += 4) {
            float4 a[8];
#pragma unroll
            for (int j = 0; j < 8; ++j)
                a[j] = *(const float4*)&sIn[(tr * 8 + j) * LDI + kk];
#pragma unroll
            for (int t = 0; t < 4; ++t) {
                float4 w0 = *(const float4*)&sW[(kk + t) * COUT + tc * 4];
                float4 w1;
                if constexpr (CT == 8)
                    w1 = *(const float4*)&sW[(kk + t) * COUT + COUT / 2 + tc * 4];
#pragma unroll
                for (int j = 0; j < 8; ++j) {
                    float av = (t == 0) ? a[j].x : (t == 1) ? a[j].y
                             : (t == 2) ? a[j].z : a[j].w;
                    acc[j][0] = fmaf(av, w0.x, acc[j][0]);
                    acc[j][1] = fmaf(av, w0.y, acc[j][1]);
                    acc[j][2] = fmaf(av, w0.z, acc[j][2]);
                    acc[j][3] = fmaf(av, w0.w, acc[j][3]);
                    if constexpr (CT == 8) {
                        acc[j][4] = fmaf(av, w1.x, acc[j][4]);
                        acc[j][5] = fmaf(av, w1.y, acc[j][5]);
                        acc[j][6] = fmaf(av, w1.z, acc[j][6]);
                        acc[j][7] = fmaf(av, w1.w, acc[j][7]);
                    }
                }
            }
        }
        __syncthreads();
    }

#pragma unroll
    for (int j = 0; j < 8; ++j) {
        int gr = row0 + tr * 8 + j;
        if (gr < n) {
            float dv = dinv[gr];
            float4 o0 = {acc[j][0] * dv, acc[j][1] * dv, acc[j][2] * dv, acc[j][3] * dv};
            *(float4*)&out[(size_t)gr * COUT + tc * 4] = o0;
            if constexpr (CT == 8) {
                float4 o1 = {acc[j][4] * dv, acc[j][5] * dv, acc[j][6] * dv, acc[j][7] * dv};
                *(float4*)&out[(size_t)gr * COUT + COUT / 2 + tc * 4] = o1;
            }
        }
    }
}

// heads matmul: out = g3 (N x 64) @ Wcat (64 x 128) + [bmu|bls] -> mu, ls
// Same BM=128/KC=32 tiling; no relu, no dinv.
__global__ __launch_bounds__(256) void k_mm_heads(const float* __restrict__ in,
                                                  const float* __restrict__ W,
                                                  const float* __restrict__ bmu,
                                                  const float* __restrict__ bls,
                                                  float* __restrict__ mu,
                                                  float* __restrict__ ls, int n) {
    constexpr int BM = 128, KC = 32, LDI = KC + 4, K = 64, COUT = 128;
    __shared__ float sIn[BM * LDI];
    __shared__ float sW[KC * COUT];

    const int tid = threadIdx.x;
    const int row0 = blockIdx.x * BM;
    const int tc = tid & 15;
    const int tr = tid >> 4;

    float acc[8][8];
#pragma unroll
    for (int j = 0; j < 8; ++j)
#pragma unroll
        for (int c = 0; c < 8; ++c) acc[j][c] = 0.f;

    const int sr = tid >> 3;
    const int sk = (tid & 7) * 4;

    for (int kc = 0; kc < K; kc += KC) {
#pragma unroll
        for (int p = 0; p < 4; ++p) {
            int rr = p * 32 + sr;
            int gr = row0 + rr;
            float4 v = {0.f, 0.f, 0.f, 0.f};
            if (gr < n) v = *(const float4*)&in[(size_t)gr * K + kc + sk];
            *(float4*)&sIn[rr * LDI + sk] = v;
        }
        for (int f4 = tid; f4 < KC * COUT / 4; f4 += 256)
            *(float4*)&sW[f4 * 4] = *(const float4*)&W[(size_t)kc * COUT + f4 * 4];
        __syncthreads();

        for (int kk = 0; kk < KC; kk += 4) {
            float4 a[8];
#pragma unroll
            for (int j = 0; j < 8; ++j)
                a[j] = *(const float4*)&sIn[(tr * 8 + j) * LDI + kk];
#pragma unroll
            for (int t = 0; t < 4; ++t) {
                float4 w0 = *(const float4*)&sW[(kk + t) * COUT + tc * 4];
                float4 w1 = *(const float4*)&sW[(kk + t) * COUT + 64 + tc * 4];
#pragma unroll
                for (int j = 0; j < 8; ++j) {
                    float av = (t == 0) ? a[j].x : (t == 1) ? a[j].y
                             : (t == 2) ? a[j].z : a[j].w;
                    acc[j][0] = fmaf(av, w0.x, acc[j][0]);
                    acc[j][1] = fmaf(av, w0.y, acc[j][1]);
                    acc[j][2] = fmaf(av, w0.z, acc[j][2]);
                    acc[j][3] = fmaf(av, w0.w, acc[j][3]);
                    acc[j][4] = fmaf(av, w1.x, acc[j][4]);
                    acc[j][5] = fmaf(av, w1.y, acc[j][5]);
                    acc[j][6] = fmaf(av, w1.z, acc[j][6]);
                    acc[j][7] = fmaf(av, w1.w, acc[j][7]);
                }
            }
        }
        __syncthreads();
    }

    float4 bm = ((const float4*)bmu)[tc];
    float4 bl = ((const float4*)bls)[tc];
#pragma unroll
    for (int j = 0; j < 8; ++j) {
        int gr = row0 + tr * 8 + j;
        if (gr < n) {
            float4 o0 = {acc[j][0] + bm.x, acc[j][1] + bm.y, acc[j][2] + bm.z, acc[j][3] + bm.w};
            float4 o1 = {acc[j][4] + bl.x, acc[j][5] + bl.y, acc[j][6] + bl.z, acc[j][7] + bl.w};
            *(float4*)&mu[(size_t)gr * 64 + tc * 4] = o0;
            *(float4*)&ls[(size_t)gr * 64 + tc * 4] = o1;
        }
    }
}

// 128-wide packed gather (layer 2): 32 lanes x float4 = one full row ->
// 2 edges per wave-instruction; 16 edges/iteration, masked. shfl_xor(32).
__global__ __launch_bounds__(256) void k_gather128p(const float* __restrict__ tab,
                                                    const int* __restrict__ rptr,
                                                    const int* __restrict__ col,
                                                    const float* __restrict__ dinv,
                                                    const float* __restrict__ b,
                                                    float* __restrict__ out, int n) {
    const int wave = threadIdx.x >> 6;
    const int lane = threadIdx.x & 63;
    const int g = lane >> 5;
    const int q = lane & 31;
    const int node = blockIdx.x * 4 + wave;
    if (node >= n) return;
    const int beg = rptr[node], end = rptr[node + 1];

    float4 acc = {0.f, 0.f, 0.f, 0.f};
    int j = beg;
    if (j < end) {
        int s[8]; bool val[8];
#pragma unroll
        for (int u = 0; u < 8; ++u) {
            int ei = j + 2 * u + g;
            val[u] = ei < end;
            s[u] = val[u] ? col[ei] : node;
        }
        j += 16;
        while (true) {
            float4 v[8];
#pragma unroll
            for (int u = 0; u < 8; ++u)
                v[u] = *(const float4*)&tab[(size_t)s[u] * 128 + q * 4];
            const bool more = j < end;
            int sn[8]; bool vn[8];
            if (more) {
#pragma unroll
                for (int u = 0; u < 8; ++u) {
                    int ei = j + 2 * u + g;
                    vn[u] = ei < end;
                    sn[u] = vn[u] ? col[ei] : node;
                }
            }
#pragma unroll
            for (int u = 0; u < 8; ++u) {
                if (val[u]) {
                    acc.x += v[u].x; acc.y += v[u].y;
                    acc.z += v[u].z; acc.w += v[u].w;
                }
            }
            if (!more) break;
#pragma unroll
            for (int u = 0; u < 8; ++u) { s[u] = sn[u]; val[u] = vn[u]; }
            j += 16;
        }
    }
    acc.x += __shfl_xor(acc.x, 32, 64); acc.y += __shfl_xor(acc.y, 32, 64);
    acc.z += __shfl_xor(acc.z, 32, 64); acc.w += __shfl_xor(acc.w, 32, 64);

    if (g == 0) {
        float4 self = *(const float4*)&tab[(size_t)node * 128 + q * 4];
        float dn = dinv[node];
        float4 bb = ((const float4*)b)[q];
        float4 o = {(acc.x + self.x) * dn + bb.x, (acc.y + self.y) * dn + bb.y,
                    (acc.z + self.z) * dn + bb.z, (acc.w + self.w) * dn + bb.w};
        *(float4*)&out[(size_t)node * 128 + q * 4] = o;
    }
}

// 64-wide packed gather: 16 lanes x float4 = one full row -> 4 edges/instr.
// MODE 1: out = dn*relu(o + b)  (layer 3);  MODE 2: out = o  (head pre-gather)
template <int MODE>
__global__ __launch_bounds__(256) void k_gather64p(const float* __restrict__ tab,
                                                   const int* __restrict__ rptr,
                                                   const int* __restrict__ col,
                                                   const float* __restrict__ dinv,
                                                   const float* __restrict__ b,
                                                   float* __restrict__ out, int n) {
    const int wave = threadIdx.x >> 6;
    const int lane = threadIdx.x & 63;
    const int g = lane >> 4;
    const int q = lane & 15;
    const int node = blockIdx.x * 4 + wave;
    if (node >= n) return;
    const int beg = rptr[node], end = rptr[node + 1];

    float4 acc = {0.f, 0.f, 0.f, 0.f};
    int j = beg;
    if (j < end) {
        int s[4]; bool val[4];
#pragma unroll
        for (int u = 0; u < 4; ++u) {
            int ei = j + 4 * u + g;
            val[u] = ei < end;
            s[u] = val[u] ? col[ei] : node;
        }
        j += 16;
        while (true) {
            float4 v[4];
#pragma unroll
            for (int u = 0; u < 4; ++u)
                v[u] = *(const float4*)&tab[(size_t)s[u] * 64 + q * 4];
            const bool more = j < end;
            int sn[4]; bool vn[4];
            if (more) {
#pragma unroll
                for (int u = 0; u < 4; ++u) {
                    int ei = j + 4 * u + g;
                    vn[u] = ei < end;
                    sn[u] = vn[u] ? col[ei] : node;
                }
            }
#pragma unroll
            for (int u = 0; u < 4; ++u) {
                if (val[u]) {
                    acc.x += v[u].x; acc.y += v[u].y;
                    acc.z += v[u].z; acc.w += v[u].w;
                }
            }
            if (!more) break;
#pragma unroll
            for (int u = 0; u < 4; ++u) { s[u] = sn[u]; val[u] = vn[u]; }
            j += 16;
        }
    }
    acc.x += __shfl_xor(acc.x, 16, 64); acc.y += __shfl_xor(acc.y, 16, 64);
    acc.z += __shfl_xor(acc.z, 16, 64); acc.w += __shfl_xor(acc.w, 16, 64);
    acc.x += __shfl_xor(acc.x, 32, 64); acc.y += __shfl_xor(acc.y, 32, 64);
    acc.z += __shfl_xor(acc.z, 32, 64); acc.w += __shfl_xor(acc.w, 32, 64);

    if (g == 0) {
        float4 self = *(const float4*)&tab[(size_t)node * 64 + q * 4];
        float dn = dinv[node];
        float4 o = {(acc.x + self.x) * dn, (acc.y + self.y) * dn,
                    (acc.z + self.z) * dn, (acc.w + self.w) * dn};
        if constexpr (MODE == 1) {
            float4 bb = ((const float4*)b)[q];
            o.x = fmaxf(o.x + bb.x, 0.f) * dn;
            o.y = fmaxf(o.y + bb.y, 0.f) * dn;
            o.z = fmaxf(o.z + bb.z, 0.f) * dn;
            o.w = fmaxf(o.w + bb.w, 0.f) * dn;
        }
        *(float4*)&out[(size_t)node * 64 + q * 4] = o;
    }
}

extern "C" void kernel_launch(void* const* d_in, const int* in_sizes, int n_in,
                              void* d_out, int out_size, void* d_ws, size_t ws_size,
                              hipStream_t stream) {
    const int*   x    = (const int*)d_in[0];
    const int*   ei   = (const int*)d_in[1];
    const float* embW = (const float*)d_in[2];
    const float* W1   = (const float*)d_in[3];
    const float* b1   = (const float*)d_in[4];
    const float* W2   = (const float*)d_in[5];
    const float* b2   = (const float*)d_in[6];
    const float* W3   = (const float*)d_in[7];
    const float* b3   = (const float*)d_in[8];
    const float* Wmu  = (const float*)d_in[9];
    const float* bmu  = (const float*)d_in[10];
    const float* Wls  = (const float*)d_in[11];
    const float* bls  = (const float*)d_in[12];

    const int n = in_sizes[0];
    const int e = in_sizes[1] / 2;
    const int V = in_sizes[2] / 128;
    const int* src = ei;
    const int* dst = ei + e;

    char* w = (char*)d_ws;
    auto alloc = [&](size_t bytes) {
        char* p = w;
        w += (bytes + 255) & ~(size_t)255;
        return p;
    };
    float* bufA = (float*)alloc((size_t)n * 128 * 4);
    float* bufB = (float*)alloc((size_t)n * 128 * 4);
    float* hW   = (float*)alloc((size_t)n * 128 * 4);
    int*   rptr = (int*)alloc((size_t)(n + 1) * 4);
    int*   col  = (int*)alloc((size_t)e * 4);
    int*   pck  = (int*)alloc((size_t)e * 4);
    float* dinv = (float*)alloc((size_t)n * 4);
    int2*  xd   = (int2*)alloc((size_t)n * 8);
    float* Wcat = (float*)alloc((size_t)64 * 128 * 4);
    float* Msm  = (float*)alloc((size_t)32 * 128 * 4);
    int*   bcnt = (int*)alloc((size_t)256 * 4);
    int*   boff = (int*)alloc((size_t)257 * 4);
    int*   gcur = (int*)alloc((size_t)256 * 4);

    const int nbuck = (n + 255) / 256;
    const int ntile = (e + 4095) / 4096;

    // ---- bucketed CSR build (reused by all layers) ----
    hipMemsetAsync(bcnt, 0, (size_t)256 * 4, stream);
    hipMemsetAsync(gcur, 0, (size_t)256 * 4, stream);
    k_bcount<<<ntile, 256, 0, stream>>>(dst, bcnt, e);
    k_bscan <<<1, 256, 0, stream>>>(bcnt, boff);
    k_binA2 <<<ntile, 256, 0, stream>>>(src, dst, boff, gcur, pck, e, nbuck);
    k_binB2 <<<nbuck, 256, 0, stream>>>(pck, boff, x, rptr, dinv, xd, col, n);
    k_smallmm<<<(V + 1) / 2, 256, 0, stream>>>(embW, W1, Msm, V);
    k_catW <<<(64 * 128 + 255) / 256, 256, 0, stream>>>(Wmu, Wls, Wcat);

    const int gmm = (n + 127) / 128;
    const int ggt = (n + 3) / 4;
    float* mu = (float*)d_out;
    float* ls = (float*)d_out + (size_t)n * 64;

    // layer 1: 28-row LDS-table gather
    k_gather_l1<<<ggt, 256, 0, stream>>>(Msm, rptr, col, xd, b1, bufA, n, V);
    // layer 2: matmul (relu on load) + packed 128-wide gather
    k_matmul<128, 128, true><<<gmm, 256, 0, stream>>>(bufA, W2, dinv, hW, n);
    k_gather128p<<<ggt, 256, 0, stream>>>(hW, rptr, col, dinv, b2, bufB, n);
    // layer 3: matmul 128->64 + packed 64-wide gather, out = dinv*relu(conv3)
    k_matmul<128, 64, true><<<gmm, 256, 0, stream>>>(bufB, W3, dinv, hW, n);
    k_gather64p<1><<<ggt, 256, 0, stream>>>(hW, rptr, col, dinv, b3, bufA, n);
    // heads: g3 = A*(dinv*relu(conv3)) packed gather, then 64->128 matmul
    k_gather64p<2><<<ggt, 256, 0, stream>>>(bufA, rptr, col, dinv, bmu, bufB, n);
    k_mm_heads<<<gmm, 256, 0, stream>>>(bufB, Wcat, bmu, bls, mu, ls, n);
}